// Round 6
// baseline (245.103 us; speedup 1.0000x reference)
//
#include <hip/hip_runtime.h>
#include <cstdint>
#include <cstddef>

typedef __bf16 bf16_t;
typedef __bf16 bf16x8 __attribute__((ext_vector_type(8)));
typedef float f32x4 __attribute__((ext_vector_type(4)));

static constexpr int SEQ = 2048;
static constexpr int DMODEL = 1024;
static constexpr int HEADS = 16;
static constexpr int DK = 64;
static constexpr int MROWS = 4 * SEQ;               // B*S = 8192
static constexpr size_t NEC = (size_t)MROWS * DMODEL; // 8M elems
static constexpr size_t WEC = (size_t)DMODEL * DMODEL; // 1M elems

// ---------------- fused fp32 -> bf16 cast for all 7 arrays ----------------
__global__ __launch_bounds__(256) void cast_all(const float* __restrict__ q,
                                                const float* __restrict__ k,
                                                const float* __restrict__ v,
                                                const float* __restrict__ wq,
                                                const float* __restrict__ wk,
                                                const float* __restrict__ wv,
                                                const float* __restrict__ wo,
                                                bf16_t* __restrict__ out) {
  size_t i = (size_t)blockIdx.x * 256 + threadIdx.x;
  size_t e = i * 8;
  const float* src;
  size_t off;
  if (e < NEC) { src = q; off = e; }
  else if (e < 2 * NEC) { src = k; off = e - NEC; }
  else if (e < 3 * NEC) { src = v; off = e - 2 * NEC; }
  else if (e < 3 * NEC + WEC) { src = wq; off = e - 3 * NEC; }
  else if (e < 3 * NEC + 2 * WEC) { src = wk; off = e - 3 * NEC - WEC; }
  else if (e < 3 * NEC + 3 * WEC) { src = wv; off = e - 3 * NEC - 2 * WEC; }
  else { src = wo; off = e - 3 * NEC - 3 * WEC; }
  const float4* p = reinterpret_cast<const float4*>(src + off);
  float4 a = p[0], b = p[1];
  bf16x8 o;
  o[0] = (bf16_t)a.x; o[1] = (bf16_t)a.y; o[2] = (bf16_t)a.z; o[3] = (bf16_t)a.w;
  o[4] = (bf16_t)b.x; o[5] = (bf16_t)b.y; o[6] = (bf16_t)b.z; o[7] = (bf16_t)b.w;
  *(reinterpret_cast<bf16x8*>(out + e)) = o;
}

// ---------------- async global -> LDS, 16B per lane ----------------
__device__ __forceinline__ void async16(const bf16_t* g, bf16_t* l) {
  __builtin_amdgcn_global_load_lds((const __attribute__((address_space(1))) void*)g,
                                   (__attribute__((address_space(3))) void*)l,
                                   16, 0, 0);
}

// ================= merged Q/K/V projection GEMM, 256x256 tile =================
// grid = 384 blocks (3 segs x 128 tiles), 512 threads = 8 waves (2M x 4N),
// wave tile 128x64 (8x4 16x16 frags). BK=32, LDS 64KB double-buffered.
// Counted-vmcnt pipeline: loads for K-tile t+1 stay in flight across both
// barriers of tile t (s_waitcnt vmcnt(4), never 0 in the main loop).
// Publish pattern: each wave waits for ITS OWN tile-t loads (vmcnt(4)),
// then barrier => all waves' tile-t loads complete. Second barrier after
// lgkmcnt(0) publishes "all reads done" so buf[t&1] is safe to overwrite
// at iteration t+1 (stage targets buf[(t+2)&1] only after that barrier).
// Slot-swizzle (slot ^= row&3) applied on pre-swizzled global source
// (gll dest is linear) and on ds_read addresses.
__global__ __launch_bounds__(512, 2) void gemm_qkv(const bf16_t* __restrict__ Abase,
                                                   const bf16_t* __restrict__ Wbase,
                                                   const float* __restrict__ bq,
                                                   const float* __restrict__ bk,
                                                   const float* __restrict__ bv,
                                                   float scaleQ,
                                                   bf16_t* __restrict__ QKbase,
                                                   bf16_t* __restrict__ Vt) {
  __shared__ __align__(16) bf16_t sA[2][256 * 32];
  __shared__ __align__(16) bf16_t sB[2][256 * 32];
  const int tid = threadIdx.x;
  const int lane = tid & 63;
  const int w = tid >> 6;            // 0..7
  const int wm = w >> 2, wn = w & 3; // 2 x 4 wave grid
  const int l16 = lane & 15, l4 = lane >> 4;
  const int sr4 = lane >> 2, c4 = lane & 3; // staging: 16 rows x 4 slots per wave-instr

  // XCD-chunked bijective swizzle (384 = 8 * 48)
  int bid = blockIdx.x;
  int swz = (bid & 7) * 48 + (bid >> 3);
  const int seg = swz >> 7;    // 0,1,2 (128 tiles per seg)
  const int inner = swz & 127;
  const bf16_t* A = Abase + (size_t)seg * NEC;
  const bf16_t* Bw = Wbase + (size_t)seg * WEC;
  const float* bias = seg == 0 ? bq : (seg == 1 ? bk : bv);
  const float scale = seg == 0 ? scaleQ : 1.0f;
  const int bm = inner >> 2, bn = inner & 3; // 32 x 4 tiles of 256
  const int m0 = bm << 8, n0 = bn << 8;

  f32x4 acc[8][4] = {};

  // stage K-tile (k0) into buffer bb: 4 gll/thread (A:2 + B:2)
  auto stage = [&](int bb, int k0) {
#pragma unroll
    for (int g = 0; g < 2; ++g) {
      int row = g * 128 + w * 16 + sr4;           // 0..255
      int cs = (c4 ^ (sr4 & 3)) * 8;              // pre-swizzled source slot
      bf16_t* dA = &sA[bb][(g * 128 + w * 16) * 32];
      bf16_t* dB = &sB[bb][(g * 128 + w * 16) * 32];
      async16(A + (size_t)(m0 + row) * DMODEL + k0 + cs, dA);
      async16(Bw + (size_t)(n0 + row) * DMODEL + k0 + cs, dB);
    }
  };

  stage(0, 0);
  const int NKT = DMODEL / 32; // 32
  for (int t = 0; t < NKT; ++t) {
    if (t + 1 < NKT) {
      stage((t + 1) & 1, (t + 1) * 32);
      asm volatile("s_waitcnt vmcnt(4)" ::: "memory"); // own tile-t loads done
    } else {
      asm volatile("s_waitcnt vmcnt(0)" ::: "memory");
    }
    __builtin_amdgcn_s_barrier();    // => ALL waves' tile-t loads landed
    const bf16_t* bA = sA[t & 1];
    const bf16_t* bB = sB[t & 1];
    bf16x8 af[8], bf[4];
#pragma unroll
    for (int i = 0; i < 8; ++i) {
      int row = wm * 128 + i * 16 + l16;
      int slot = l4 ^ (row & 3);
      af[i] = *reinterpret_cast<const bf16x8*>(&bA[row * 32 + slot * 8]);
    }
#pragma unroll
    for (int j = 0; j < 4; ++j) {
      int row = wn * 64 + j * 16 + l16;
      int slot = l4 ^ (row & 3);
      bf[j] = *reinterpret_cast<const bf16x8*>(&bB[row * 32 + slot * 8]);
    }
    asm volatile("s_waitcnt lgkmcnt(0)" ::: "memory"); // own reads landed
    __builtin_amdgcn_sched_barrier(0);
    __builtin_amdgcn_s_barrier();    // => buf[t&1] reusable next iteration
    __builtin_amdgcn_s_setprio(1);
#pragma unroll
    for (int i = 0; i < 8; ++i)
#pragma unroll
      for (int j = 0; j < 4; ++j)
        acc[i][j] = __builtin_amdgcn_mfma_f32_16x16x32_bf16(af[i], bf[j], acc[i][j], 0, 0, 0);
    __builtin_amdgcn_s_setprio(0);
  }

  // epilogue
  float bj[4];
#pragma unroll
  for (int j = 0; j < 4; ++j) bj[j] = bias[n0 + wn * 64 + j * 16 + l16];

  bf16_t* outQK = QKbase + (size_t)seg * NEC;
#pragma unroll
  for (int i = 0; i < 8; ++i) {
#pragma unroll
    for (int j = 0; j < 4; ++j) {
#pragma unroll
      for (int r = 0; r < 4; ++r) {
        int m = m0 + wm * 128 + i * 16 + l4 * 4 + r;
        int n = n0 + wn * 64 + j * 16 + l16;
        float v = (acc[i][j][r] + bj[j]) * scale;
        int b = m >> 11, s = m & 2047, h = n >> 6, d = n & 63;
        if (seg < 2) {
          outQK[(((size_t)(b * HEADS + h) * SEQ + s) << 6) + d] = (bf16_t)v;
        } else {
          Vt[((size_t)(b * HEADS + h) * DK + d) * SEQ + s] = (bf16_t)v;
        }
      }
    }
  }
}

// ================= final output projection: fp32 out (unchanged) =================
__global__ __launch_bounds__(256) void gemm_out(const bf16_t* __restrict__ A,
                                                const bf16_t* __restrict__ Bw,
                                                const float* __restrict__ bias,
                                                float* __restrict__ Cout) {
  __shared__ __align__(16) bf16_t sA[128 * 32];
  __shared__ __align__(16) bf16_t sB[128 * 32];
  const int tid = threadIdx.x;
  const int lane = tid & 63;
  const int wv = tid >> 6;
  const int l16 = lane & 15, l4 = lane >> 4;

  int bid = blockIdx.x;
  int swz = (bid & 7) * 64 + (bid >> 3); // 512 = 8 * 64
  const int bm = swz >> 3, bn = swz & 7;
  const int m0 = bm << 7, n0 = bn << 7;
  const int wr = (wv >> 1) * 64, wc = (wv & 1) * 64;

  f32x4 acc[4][4] = {};

  for (int k0 = 0; k0 < DMODEL; k0 += 32) {
#pragma unroll
    for (int p = 0; p < 2; ++p) {
      int t = p * 256 + tid;
      int row = t >> 2, ks = (t & 3) * 8;
      async16(A + (size_t)(m0 + row) * DMODEL + k0 + ks, sA + (size_t)(p * 256 + wv * 64) * 8);
      async16(Bw + (size_t)(n0 + row) * DMODEL + k0 + ks, sB + (size_t)(p * 256 + wv * 64) * 8);
    }
    __syncthreads();
    bf16x8 afrag[4], bfrag[4];
#pragma unroll
    for (int f = 0; f < 4; ++f) {
      afrag[f] = *reinterpret_cast<const bf16x8*>(&sA[(wr + f * 16 + l16) * 32 + l4 * 8]);
      bfrag[f] = *reinterpret_cast<const bf16x8*>(&sB[(wc + f * 16 + l16) * 32 + l4 * 8]);
    }
#pragma unroll
    for (int i = 0; i < 4; ++i)
#pragma unroll
      for (int j = 0; j < 4; ++j)
        acc[i][j] = __builtin_amdgcn_mfma_f32_16x16x32_bf16(afrag[i], bfrag[j], acc[i][j], 0, 0, 0);
    __syncthreads();
  }

  float bj[4];
#pragma unroll
  for (int j = 0; j < 4; ++j) bj[j] = bias[n0 + wc + j * 16 + l16];

#pragma unroll
  for (int i = 0; i < 4; ++i) {
#pragma unroll
    for (int j = 0; j < 4; ++j) {
#pragma unroll
      for (int r = 0; r < 4; ++r) {
        int m = m0 + wr + i * 16 + l4 * 4 + r;
        int n = n0 + wc + j * 16 + l16;
        Cout[(size_t)m * DMODEL + n] = acc[i][j][r] + bj[j];
      }
    }
  }
}

// ---------------- flash attention (unchanged from R4/R5) ----------------
__device__ __forceinline__ int kvsrc_row(int r) {
  return (r & 32) | (((r >> 3) & 1) << 4) | (((r >> 2) & 1) << 3) |
         (((r >> 4) & 1) << 2) | (r & 3);
}

__global__ __launch_bounds__(512, 2) void attn_kernel(const bf16_t* __restrict__ Q,
                                                      const bf16_t* __restrict__ Kp,
                                                      const bf16_t* __restrict__ Vt,
                                                      bf16_t* __restrict__ AO) {
  __shared__ __align__(16) bf16_t sK[2][64 * 64];
  __shared__ __align__(16) bf16_t sV[2][64 * 64];
  const int tid = threadIdx.x;
  const int lane = tid & 63;
  const int wv = tid >> 6; // 0..7
  const int l16 = lane & 15, l4 = lane >> 4;
  const int sub8 = lane >> 3, c8 = lane & 7;

  const int nq = SEQ / 256; // 8
  int bid = blockIdx.x;
  int swz = (bid & 7) * 64 + (bid >> 3); // 512 blocks, bijective
  const int bh = swz / nq, qt = swz % nq;
  const int b = bh >> 4, h = bh & 15;
  const bf16_t* Qh = Q + (size_t)bh * SEQ * DK;
  const bf16_t* Kh = Kp + (size_t)bh * SEQ * DK;
  const bf16_t* Vh = Vt + (size_t)bh * DK * SEQ;
  const int q0 = qt * 256 + wv * 32;

  bf16x8 aq[2][2];
#pragma unroll
  for (int s = 0; s < 2; ++s)
#pragma unroll
    for (int hf = 0; hf < 2; ++hf)
      aq[s][hf] = *reinterpret_cast<const bf16x8*>(
          &Qh[(size_t)(q0 + s * 16 + l16) * DK + hf * 32 + l4 * 8]);

  bf16x8 ones;
#pragma unroll
  for (int i = 0; i < 8; ++i) ones[i] = (bf16_t)1.0f;

  f32x4 o[2][4] = {};
  f32x4 lacc[2] = {};

  auto stage = [&](int buf, int kv0) {
    int r = wv * 8 + sub8;
    int kvr = kvsrc_row(r);
    int cs = (c8 ^ sub8) << 3;
    async16(Kh + (size_t)(kv0 + kvr) * DK + cs, &sK[buf][wv * 512]);
    async16(Vh + (size_t)r * SEQ + kv0 + cs, &sV[buf][wv * 512]);
  };

  auto compute = [&](int buf) {
    const bf16_t* bK = sK[buf];
    const bf16_t* bV = sV[buf];
    f32x4 sc[2][4] = {};
    __builtin_amdgcn_s_setprio(1);
#pragma unroll
    for (int t = 0; t < 4; ++t) {
      bf16x8 kf0 = *reinterpret_cast<const bf16x8*>(
          &bK[(t * 16 + l16) * 64 + ((l4 ^ (l16 & 7)) << 3)]);
      bf16x8 kf1 = *reinterpret_cast<const bf16x8*>(
          &bK[(t * 16 + l16) * 64 + (((4 + l4) ^ (l16 & 7)) << 3)]);
#pragma unroll
      for (int s = 0; s < 2; ++s) {
        sc[s][t] = __builtin_amdgcn_mfma_f32_16x16x32_bf16(kf0, aq[s][0], sc[s][t], 0, 0, 0);
        sc[s][t] = __builtin_amdgcn_mfma_f32_16x16x32_bf16(kf1, aq[s][1], sc[s][t], 0, 0, 0);
      }
    }
    __builtin_amdgcn_s_setprio(0);
    bf16x8 pa[2][2];
#pragma unroll
    for (int s = 0; s < 2; ++s) {
#pragma unroll
      for (int t = 0; t < 4; ++t) {
#pragma unroll
        for (int j = 0; j < 4; ++j) {
          pa[s][t >> 1][(t & 1) * 4 + j] = (bf16_t)__builtin_amdgcn_exp2f(sc[s][t][j]);
        }
      }
    }
    __builtin_amdgcn_s_setprio(1);
#pragma unroll
    for (int nb = 0; nb < 4; ++nb) {
      bf16x8 vf0 = *reinterpret_cast<const bf16x8*>(
          &bV[(nb * 16 + l16) * 64 + ((l4 ^ (l16 & 7)) << 3)]);
      bf16x8 vf1 = *reinterpret_cast<const bf16x8*>(
          &bV[(nb * 16 + l16) * 64 + (((4 + l4) ^ (l16 & 7)) << 3)]);
#pragma unroll
      for (int s = 0; s < 2; ++s) {
        o[s][nb] = __builtin_amdgcn_mfma_f32_16x16x32_bf16(pa[s][0], vf0, o[s][nb], 0, 0, 0);
        o[s][nb] = __builtin_amdgcn_mfma_f32_16x16x32_bf16(pa[s][1], vf1, o[s][nb], 0, 0, 0);
      }
    }
#pragma unroll
    for (int s = 0; s < 2; ++s) {
      lacc[s] = __builtin_amdgcn_mfma_f32_16x16x32_bf16(pa[s][0], ones, lacc[s], 0, 0, 0);
      lacc[s] = __builtin_amdgcn_mfma_f32_16x16x32_bf16(pa[s][1], ones, lacc[s], 0, 0, 0);
    }
    __builtin_amdgcn_s_setprio(0);
  };

  stage(0, 0);
  __syncthreads();
  const int NT = SEQ / 64; // 32
  for (int it = 0; it < NT; ++it) {
    if (it + 1 < NT) stage((it + 1) & 1, (it + 1) * 64);
    compute(it & 1);
    __syncthreads();
  }

#pragma unroll
  for (int s = 0; s < 2; ++s) {
#pragma unroll
    for (int j = 0; j < 4; ++j) {
      float inv = 1.0f / lacc[s][j];
      int qrow = q0 + s * 16 + l4 * 4 + j;
#pragma unroll
      for (int nb = 0; nb < 4; ++nb)
        AO[((size_t)(b * SEQ + qrow)) * DMODEL + h * DK + nb * 16 + l16] =
            (bf16_t)(o[s][nb][j] * inv);
    }
  }
}

// ---------------- launcher ----------------
extern "C" void kernel_launch(void* const* d_in, const int* in_sizes, int n_in,
                              void* d_out, int out_size, void* d_ws, size_t ws_size,
                              hipStream_t stream) {
  const float* query = (const float*)d_in[0];
  const float* key_i = (const float*)d_in[1];
  const float* value = (const float*)d_in[2];
  const float* Wq = (const float*)d_in[3];
  const float* bq = (const float*)d_in[4];
  const float* Wk = (const float*)d_in[5];
  const float* bk = (const float*)d_in[6];
  const float* Wv = (const float*)d_in[7];
  const float* bv = (const float*)d_in[8];
  const float* Wo = (const float*)d_in[9];
  const float* bo = (const float*)d_in[10];
  float* out = (float*)d_out;

  bf16_t* qb = (bf16_t*)d_ws;       // qb|kb|vb contiguous (A segments)
  bf16_t* wqb = qb + 3 * NEC;       // wqb|wkb|wvb contiguous (W segments)
  bf16_t* wob = wqb + 3 * WEC;
  bf16_t* Qp = wob + WEC;           // Qp|Kp contiguous (QK output segments)
  bf16_t* Kp = Qp + NEC;
  bf16_t* Vt = Kp + NEC;
  bf16_t* AO = Vt + NEC;
  // workspace: (7*NEC + 4*WEC)*2 = 120 MiB

  size_t totE = 3 * NEC + 4 * WEC; // 28M elems
  cast_all<<<dim3((unsigned)(totE / 8 / 256)), dim3(256), 0, stream>>>(
      query, key_i, value, Wq, Wk, Wv, Wo, qb);

  const float cexp = 0.18033688f; // log2(e)/8, folded into Q projection
  gemm_qkv<<<dim3(384), dim3(512), 0, stream>>>(qb, wqb, bq, bk, bv, cexp, Qp, Vt);

  attn_kernel<<<dim3(4 * HEADS * (SEQ / 256)), 512, 0, stream>>>(Qp, Kp, Vt, AO);

  gemm_out<<<dim3(512), dim3(256), 0, stream>>>(AO, wob, bo, out);
}

// Round 7
// 221.308 us; speedup vs baseline: 1.1075x; 1.1075x over previous
//
#include <hip/hip_runtime.h>
#include <cstdint>
#include <cstddef>

typedef __bf16 bf16_t;
typedef __bf16 bf16x8 __attribute__((ext_vector_type(8)));
typedef float f32x4 __attribute__((ext_vector_type(4)));

static constexpr int SEQ = 2048;
static constexpr int DMODEL = 1024;
static constexpr int HEADS = 16;
static constexpr int DK = 64;
static constexpr int MROWS = 4 * SEQ;               // B*S = 8192
static constexpr size_t NEC = (size_t)MROWS * DMODEL; // 8M elems
static constexpr size_t WEC = (size_t)DMODEL * DMODEL; // 1M elems

// ---------------- fused fp32 -> bf16 cast for all 7 arrays ----------------
__global__ __launch_bounds__(256) void cast_all(const float* __restrict__ q,
                                                const float* __restrict__ k,
                                                const float* __restrict__ v,
                                                const float* __restrict__ wq,
                                                const float* __restrict__ wk,
                                                const float* __restrict__ wv,
                                                const float* __restrict__ wo,
                                                bf16_t* __restrict__ out) {
  size_t i = (size_t)blockIdx.x * 256 + threadIdx.x;
  size_t e = i * 8;
  const float* src;
  size_t off;
  if (e < NEC) { src = q; off = e; }
  else if (e < 2 * NEC) { src = k; off = e - NEC; }
  else if (e < 3 * NEC) { src = v; off = e - 2 * NEC; }
  else if (e < 3 * NEC + WEC) { src = wq; off = e - 3 * NEC; }
  else if (e < 3 * NEC + 2 * WEC) { src = wk; off = e - 3 * NEC - WEC; }
  else if (e < 3 * NEC + 3 * WEC) { src = wv; off = e - 3 * NEC - 2 * WEC; }
  else { src = wo; off = e - 3 * NEC - 3 * WEC; }
  const float4* p = reinterpret_cast<const float4*>(src + off);
  float4 a = p[0], b = p[1];
  bf16x8 o;
  o[0] = (bf16_t)a.x; o[1] = (bf16_t)a.y; o[2] = (bf16_t)a.z; o[3] = (bf16_t)a.w;
  o[4] = (bf16_t)b.x; o[5] = (bf16_t)b.y; o[6] = (bf16_t)b.z; o[7] = (bf16_t)b.w;
  *(reinterpret_cast<bf16x8*>(out + e)) = o;
}

// ---------------- async global -> LDS, 16B per lane ----------------
__device__ __forceinline__ void async16(const bf16_t* g, bf16_t* l) {
  __builtin_amdgcn_global_load_lds((const __attribute__((address_space(1))) void*)g,
                                   (__attribute__((address_space(3))) void*)l,
                                   16, 0, 0);
}

// Conflict-free LDS addressing for [rows][32]-elem bf16 K-tiles:
// view as [rows/2][64 elems] (128B rows = all 32 banks), slot (16B unit)
// index s3 = ((m&1)<<2)|kgroup, swizzled s3 ^= (lrow&7).
// A 16-lane fragment read then hits each slot exactly twice (2-way = free).
__device__ __forceinline__ int lds_off(int m, int l4) {
  int lr = m >> 1;
  return lr * 64 + (((((m & 1) << 2) | l4) ^ (lr & 7)) << 3);
}

// ================= merged Q/K/V projection GEMM, 128x256 tile =================
// grid = 768 blocks (3 segs x 64 x 4) = exactly 3/CU, 512 threads = 8 waves
// (2M x 4N, wave tile 64x64). BK=32, single-buffer 2-barrier loop (R5
// structure), LDS 24KB -> 3-4 blocks/CU co-resident for cross-block overlap.
// Swizzled LDS (see lds_off) with pre-swizzled global source (gll writes
// linearly: lane l covers linear bytes base + l*16).
__global__ __launch_bounds__(512, 4) void gemm_qkv(const bf16_t* __restrict__ Abase,
                                                   const bf16_t* __restrict__ Wbase,
                                                   const float* __restrict__ bq,
                                                   const float* __restrict__ bk,
                                                   const float* __restrict__ bv,
                                                   float scaleQ,
                                                   bf16_t* __restrict__ QKbase,
                                                   bf16_t* __restrict__ Vt) {
  __shared__ __align__(16) bf16_t sA[128 * 32]; // viewed as [64][64] swizzled
  __shared__ __align__(16) bf16_t sB[256 * 32]; // viewed as [128][64] swizzled
  const int tid = threadIdx.x;
  const int lane = tid & 63;
  const int w = tid >> 6;            // 0..7
  const int wm = w >> 2, wn = w & 3; // 2 x 4 wave grid
  const int l16 = lane & 15, l4 = lane >> 4;

  // XCD-chunked bijective swizzle (768 = 8 * 96)
  int bid = blockIdx.x;
  int swz = (bid & 7) * 96 + (bid >> 3);
  const int seg = swz >> 8;    // 0,1,2 (256 tiles per seg)
  const int inner = swz & 255;
  const bf16_t* A = Abase + (size_t)seg * NEC;
  const bf16_t* Bw = Wbase + (size_t)seg * WEC;
  const float* bias = seg == 0 ? bq : (seg == 1 ? bk : bv);
  const float scale = seg == 0 ? scaleQ : 1.0f;
  const int bm = inner >> 2, bn = inner & 3; // 64 x 4 tiles
  const int m0 = bm << 7, n0 = bn << 8;

  // staging source mapping (thread-fixed): lane covers LDS linear bytes
  // w*1024 + lane*16 => lrow = w*8 + (lane>>3), slot = lane&7.
  // content at (lrow, slot): sg = slot ^ (lrow&7); m = 2*lrow + (sg>>2),
  // kgroup = sg&3. (x = lrow&7 = (lane>>3)&7 independent of w, chunk.)
  const int sg = (lane & 7) ^ ((lane >> 3) & 7);
  const int mS = 2 * (w * 8 + (lane >> 3)) + (sg >> 2); // tile row 0..127
  const int gS = (sg & 3) * 8;                           // k offset (elems)

  f32x4 acc[4][4] = {};

  for (int k0 = 0; k0 < DMODEL; k0 += 32) {
    async16(A + (size_t)(m0 + mS) * DMODEL + k0 + gS, &sA[w * 512]);
    async16(Bw + (size_t)(n0 + mS) * DMODEL + k0 + gS, &sB[w * 512]);
    async16(Bw + (size_t)(n0 + 128 + mS) * DMODEL + k0 + gS, &sB[4096 + w * 512]);
    __syncthreads();
    bf16x8 af[4], bf[4];
#pragma unroll
    for (int f = 0; f < 4; ++f)
      af[f] = *reinterpret_cast<const bf16x8*>(&sA[lds_off(wm * 64 + f * 16 + l16, l4)]);
#pragma unroll
    for (int j = 0; j < 4; ++j)
      bf[j] = *reinterpret_cast<const bf16x8*>(&sB[lds_off(wn * 64 + j * 16 + l16, l4)]);
#pragma unroll
    for (int i = 0; i < 4; ++i)
#pragma unroll
      for (int j = 0; j < 4; ++j)
        acc[i][j] = __builtin_amdgcn_mfma_f32_16x16x32_bf16(af[i], bf[j], acc[i][j], 0, 0, 0);
    __syncthreads();
  }

  // epilogue
  float bj[4];
#pragma unroll
  for (int j = 0; j < 4; ++j) bj[j] = bias[n0 + wn * 64 + j * 16 + l16];

  bf16_t* outQK = QKbase + (size_t)seg * NEC;
#pragma unroll
  for (int i = 0; i < 4; ++i) {
#pragma unroll
    for (int j = 0; j < 4; ++j) {
#pragma unroll
      for (int r = 0; r < 4; ++r) {
        int m = m0 + wm * 64 + i * 16 + l4 * 4 + r;
        int n = n0 + wn * 64 + j * 16 + l16;
        float v = (acc[i][j][r] + bj[j]) * scale;
        int b = m >> 11, s = m & 2047, h = n >> 6, d = n & 63;
        if (seg < 2) {
          outQK[(((size_t)(b * HEADS + h) * SEQ + s) << 6) + d] = (bf16_t)v;
        } else {
          Vt[((size_t)(b * HEADS + h) * DK + d) * SEQ + s] = (bf16_t)v;
        }
      }
    }
  }
}

// ================= final output projection: fp32 out, 128x128 tile =================
__global__ __launch_bounds__(256, 4) void gemm_out(const bf16_t* __restrict__ A,
                                                   const bf16_t* __restrict__ Bw,
                                                   const float* __restrict__ bias,
                                                   float* __restrict__ Cout) {
  __shared__ __align__(16) bf16_t sA[128 * 32]; // [64][64] swizzled view
  __shared__ __align__(16) bf16_t sB[128 * 32];
  const int tid = threadIdx.x;
  const int lane = tid & 63;
  const int wv = tid >> 6; // 0..3
  const int l16 = lane & 15, l4 = lane >> 4;

  int bid = blockIdx.x;
  int swz = (bid & 7) * 64 + (bid >> 3); // 512 = 8 * 64
  const int bm = swz >> 3, bn = swz & 7;
  const int m0 = bm << 7, n0 = bn << 7;
  const int wr = (wv >> 1) * 64, wc = (wv & 1) * 64;

  // staging: 2 chunks/thread per tile; chunk c covers LDS bytes
  // c*4096 + wv*1024 + lane*16 => lrow = c*32 + wv*8 + (lane>>3), slot = lane&7
  const int sg = (lane & 7) ^ ((lane >> 3) & 7);
  const int mS = 2 * (wv * 8 + (lane >> 3)) + (sg >> 2); // + c*64
  const int gS = (sg & 3) * 8;

  f32x4 acc[4][4] = {};

  for (int k0 = 0; k0 < DMODEL; k0 += 32) {
#pragma unroll
    for (int c = 0; c < 2; ++c) {
      async16(A + (size_t)(m0 + c * 64 + mS) * DMODEL + k0 + gS, &sA[c * 2048 + wv * 512]);
      async16(Bw + (size_t)(n0 + c * 64 + mS) * DMODEL + k0 + gS, &sB[c * 2048 + wv * 512]);
    }
    __syncthreads();
    bf16x8 afrag[4], bfrag[4];
#pragma unroll
    for (int f = 0; f < 4; ++f) {
      afrag[f] = *reinterpret_cast<const bf16x8*>(&sA[lds_off(wr + f * 16 + l16, l4)]);
      bfrag[f] = *reinterpret_cast<const bf16x8*>(&sB[lds_off(wc + f * 16 + l16, l4)]);
    }
#pragma unroll
    for (int i = 0; i < 4; ++i)
#pragma unroll
      for (int j = 0; j < 4; ++j)
        acc[i][j] = __builtin_amdgcn_mfma_f32_16x16x32_bf16(afrag[i], bfrag[j], acc[i][j], 0, 0, 0);
    __syncthreads();
  }

  float bj[4];
#pragma unroll
  for (int j = 0; j < 4; ++j) bj[j] = bias[n0 + wc + j * 16 + l16];

#pragma unroll
  for (int i = 0; i < 4; ++i) {
#pragma unroll
    for (int j = 0; j < 4; ++j) {
#pragma unroll
      for (int r = 0; r < 4; ++r) {
        int m = m0 + wr + i * 16 + l4 * 4 + r;
        int n = n0 + wc + j * 16 + l16;
        Cout[(size_t)m * DMODEL + n] = acc[i][j][r] + bj[j];
      }
    }
  }
}

// ---------------- flash attention (unchanged from R4/R5) ----------------
__device__ __forceinline__ int kvsrc_row(int r) {
  return (r & 32) | (((r >> 3) & 1) << 4) | (((r >> 2) & 1) << 3) |
         (((r >> 4) & 1) << 2) | (r & 3);
}

__global__ __launch_bounds__(512, 2) void attn_kernel(const bf16_t* __restrict__ Q,
                                                      const bf16_t* __restrict__ Kp,
                                                      const bf16_t* __restrict__ Vt,
                                                      bf16_t* __restrict__ AO) {
  __shared__ __align__(16) bf16_t sK[2][64 * 64];
  __shared__ __align__(16) bf16_t sV[2][64 * 64];
  const int tid = threadIdx.x;
  const int lane = tid & 63;
  const int wv = tid >> 6; // 0..7
  const int l16 = lane & 15, l4 = lane >> 4;
  const int sub8 = lane >> 3, c8 = lane & 7;

  const int nq = SEQ / 256; // 8
  int bid = blockIdx.x;
  int swz = (bid & 7) * 64 + (bid >> 3); // 512 blocks, bijective
  const int bh = swz / nq, qt = swz % nq;
  const int b = bh >> 4, h = bh & 15;
  const bf16_t* Qh = Q + (size_t)bh * SEQ * DK;
  const bf16_t* Kh = Kp + (size_t)bh * SEQ * DK;
  const bf16_t* Vh = Vt + (size_t)bh * DK * SEQ;
  const int q0 = qt * 256 + wv * 32;

  bf16x8 aq[2][2];
#pragma unroll
  for (int s = 0; s < 2; ++s)
#pragma unroll
    for (int hf = 0; hf < 2; ++hf)
      aq[s][hf] = *reinterpret_cast<const bf16x8*>(
          &Qh[(size_t)(q0 + s * 16 + l16) * DK + hf * 32 + l4 * 8]);

  bf16x8 ones;
#pragma unroll
  for (int i = 0; i < 8; ++i) ones[i] = (bf16_t)1.0f;

  f32x4 o[2][4] = {};
  f32x4 lacc[2] = {};

  auto stage = [&](int buf, int kv0) {
    int r = wv * 8 + sub8;
    int kvr = kvsrc_row(r);
    int cs = (c8 ^ sub8) << 3;
    async16(Kh + (size_t)(kv0 + kvr) * DK + cs, &sK[buf][wv * 512]);
    async16(Vh + (size_t)r * SEQ + kv0 + cs, &sV[buf][wv * 512]);
  };

  auto compute = [&](int buf) {
    const bf16_t* bK = sK[buf];
    const bf16_t* bV = sV[buf];
    f32x4 sc[2][4] = {};
    __builtin_amdgcn_s_setprio(1);
#pragma unroll
    for (int t = 0; t < 4; ++t) {
      bf16x8 kf0 = *reinterpret_cast<const bf16x8*>(
          &bK[(t * 16 + l16) * 64 + ((l4 ^ (l16 & 7)) << 3)]);
      bf16x8 kf1 = *reinterpret_cast<const bf16x8*>(
          &bK[(t * 16 + l16) * 64 + (((4 + l4) ^ (l16 & 7)) << 3)]);
#pragma unroll
      for (int s = 0; s < 2; ++s) {
        sc[s][t] = __builtin_amdgcn_mfma_f32_16x16x32_bf16(kf0, aq[s][0], sc[s][t], 0, 0, 0);
        sc[s][t] = __builtin_amdgcn_mfma_f32_16x16x32_bf16(kf1, aq[s][1], sc[s][t], 0, 0, 0);
      }
    }
    __builtin_amdgcn_s_setprio(0);
    bf16x8 pa[2][2];
#pragma unroll
    for (int s = 0; s < 2; ++s) {
#pragma unroll
      for (int t = 0; t < 4; ++t) {
#pragma unroll
        for (int j = 0; j < 4; ++j) {
          pa[s][t >> 1][(t & 1) * 4 + j] = (bf16_t)__builtin_amdgcn_exp2f(sc[s][t][j]);
        }
      }
    }
    __builtin_amdgcn_s_setprio(1);
#pragma unroll
    for (int nb = 0; nb < 4; ++nb) {
      bf16x8 vf0 = *reinterpret_cast<const bf16x8*>(
          &bV[(nb * 16 + l16) * 64 + ((l4 ^ (l16 & 7)) << 3)]);
      bf16x8 vf1 = *reinterpret_cast<const bf16x8*>(
          &bV[(nb * 16 + l16) * 64 + (((4 + l4) ^ (l16 & 7)) << 3)]);
#pragma unroll
      for (int s = 0; s < 2; ++s) {
        o[s][nb] = __builtin_amdgcn_mfma_f32_16x16x32_bf16(pa[s][0], vf0, o[s][nb], 0, 0, 0);
        o[s][nb] = __builtin_amdgcn_mfma_f32_16x16x32_bf16(pa[s][1], vf1, o[s][nb], 0, 0, 0);
      }
    }
#pragma unroll
    for (int s = 0; s < 2; ++s) {
      lacc[s] = __builtin_amdgcn_mfma_f32_16x16x32_bf16(pa[s][0], ones, lacc[s], 0, 0, 0);
      lacc[s] = __builtin_amdgcn_mfma_f32_16x16x32_bf16(pa[s][1], ones, lacc[s], 0, 0, 0);
    }
    __builtin_amdgcn_s_setprio(0);
  };

  stage(0, 0);
  __syncthreads();
  const int NT = SEQ / 64; // 32
  for (int it = 0; it < NT; ++it) {
    if (it + 1 < NT) stage((it + 1) & 1, (it + 1) * 64);
    compute(it & 1);
    __syncthreads();
  }

#pragma unroll
  for (int s = 0; s < 2; ++s) {
#pragma unroll
    for (int j = 0; j < 4; ++j) {
      float inv = 1.0f / lacc[s][j];
      int qrow = q0 + s * 16 + l4 * 4 + j;
#pragma unroll
      for (int nb = 0; nb < 4; ++nb)
        AO[((size_t)(b * SEQ + qrow)) * DMODEL + h * DK + nb * 16 + l16] =
            (bf16_t)(o[s][nb][j] * inv);
    }
  }
}

// ---------------- launcher ----------------
extern "C" void kernel_launch(void* const* d_in, const int* in_sizes, int n_in,
                              void* d_out, int out_size, void* d_ws, size_t ws_size,
                              hipStream_t stream) {
  const float* query = (const float*)d_in[0];
  const float* key_i = (const float*)d_in[1];
  const float* value = (const float*)d_in[2];
  const float* Wq = (const float*)d_in[3];
  const float* bq = (const float*)d_in[4];
  const float* Wk = (const float*)d_in[5];
  const float* bk = (const float*)d_in[6];
  const float* Wv = (const float*)d_in[7];
  const float* bv = (const float*)d_in[8];
  const float* Wo = (const float*)d_in[9];
  const float* bo = (const float*)d_in[10];
  float* out = (float*)d_out;

  bf16_t* qb = (bf16_t*)d_ws;       // qb|kb|vb contiguous (A segments)
  bf16_t* wqb = qb + 3 * NEC;       // wqb|wkb|wvb contiguous (W segments)
  bf16_t* wob = wqb + 3 * WEC;
  bf16_t* Qp = wob + WEC;           // Qp|Kp contiguous (QK output segments)
  bf16_t* Kp = Qp + NEC;
  bf16_t* Vt = Kp + NEC;
  bf16_t* AO = Vt + NEC;
  // workspace: (7*NEC + 4*WEC)*2 = 120 MiB

  size_t totE = 3 * NEC + 4 * WEC; // 28M elems
  cast_all<<<dim3((unsigned)(totE / 8 / 256)), dim3(256), 0, stream>>>(
      query, key_i, value, Wq, Wk, Wv, Wo, qb);

  const float cexp = 0.18033688f; // log2(e)/8, folded into Q projection
  gemm_qkv<<<dim3(768), dim3(512), 0, stream>>>(qb, wqb, bq, bk, bv, cexp, Qp, Vt);

  attn_kernel<<<dim3(4 * HEADS * (SEQ / 256)), 512, 0, stream>>>(Qp, Kp, Vt, AO);

  gemm_out<<<dim3(512), dim3(256), 0, stream>>>(AO, wob, bo, out);
}

// Round 8
// 217.941 us; speedup vs baseline: 1.1246x; 1.0154x over previous
//
#include <hip/hip_runtime.h>
#include <cstdint>
#include <cstddef>

typedef __bf16 bf16_t;
typedef __bf16 bf16x8 __attribute__((ext_vector_type(8)));
typedef float f32x4 __attribute__((ext_vector_type(4)));

static constexpr int SEQ = 2048;
static constexpr int DMODEL = 1024;
static constexpr int HEADS = 16;
static constexpr int DK = 64;
static constexpr int MROWS = 4 * SEQ;               // B*S = 8192
static constexpr size_t NEC = (size_t)MROWS * DMODEL; // 8M elems
static constexpr size_t WEC = (size_t)DMODEL * DMODEL; // 1M elems

// ---------------- fused fp32 -> bf16 cast for all 7 arrays ----------------
__global__ __launch_bounds__(256) void cast_all(const float* __restrict__ q,
                                                const float* __restrict__ k,
                                                const float* __restrict__ v,
                                                const float* __restrict__ wq,
                                                const float* __restrict__ wk,
                                                const float* __restrict__ wv,
                                                const float* __restrict__ wo,
                                                bf16_t* __restrict__ out) {
  size_t i = (size_t)blockIdx.x * 256 + threadIdx.x;
  size_t e = i * 8;
  const float* src;
  size_t off;
  if (e < NEC) { src = q; off = e; }
  else if (e < 2 * NEC) { src = k; off = e - NEC; }
  else if (e < 3 * NEC) { src = v; off = e - 2 * NEC; }
  else if (e < 3 * NEC + WEC) { src = wq; off = e - 3 * NEC; }
  else if (e < 3 * NEC + 2 * WEC) { src = wk; off = e - 3 * NEC - WEC; }
  else if (e < 3 * NEC + 3 * WEC) { src = wv; off = e - 3 * NEC - 2 * WEC; }
  else { src = wo; off = e - 3 * NEC - 3 * WEC; }
  const float4* p = reinterpret_cast<const float4*>(src + off);
  float4 a = p[0], b = p[1];
  bf16x8 o;
  o[0] = (bf16_t)a.x; o[1] = (bf16_t)a.y; o[2] = (bf16_t)a.z; o[3] = (bf16_t)a.w;
  o[4] = (bf16_t)b.x; o[5] = (bf16_t)b.y; o[6] = (bf16_t)b.z; o[7] = (bf16_t)b.w;
  *(reinterpret_cast<bf16x8*>(out + e)) = o;
}

// ---------------- async global -> LDS, 16B per lane ----------------
__device__ __forceinline__ void async16(const bf16_t* g, bf16_t* l) {
  __builtin_amdgcn_global_load_lds((const __attribute__((address_space(1))) void*)g,
                                   (__attribute__((address_space(3))) void*)l,
                                   16, 0, 0);
}

// Conflict-free LDS addressing for [rows][32]-elem bf16 K-tiles:
// view as [rows/2][64 elems] (128B rows = all 32 banks), slot (16B unit)
// index s3 = ((m&1)<<2)|kgroup, swizzled s3 ^= (lrow&7).
// A 16-lane fragment read hits each slot exactly twice (2-way = free).
__device__ __forceinline__ int lds_off(int m, int l4) {
  int lr = m >> 1;
  return lr * 64 + (((((m & 1) << 2) | l4) ^ (lr & 7)) << 3);
}

// ================= merged Q/K/V projection GEMM, 128x256 tile =================
// grid = 768 blocks (3 segs x 64 x 4) = 3/CU, 512 threads = 8 waves (2Mx4N,
// wave tile 64x64). BK=32. DOUBLE-buffered LDS (48KB), ONE barrier per K-step
// (attn-style 2-phase): stage(t+1)->compute(t)->__syncthreads. The barrier's
// implicit vmcnt(0) drain lands after the compute, so staging latency hides
// under the MFMA cluster instead of being exposed between stage and barrier.
// Race-free: a wave reaches the barrier only after its lgkm-waited reads of
// buf completed, so overwriting buf at the next iter top is safe.
__global__ __launch_bounds__(512, 4) void gemm_qkv(const bf16_t* __restrict__ Abase,
                                                   const bf16_t* __restrict__ Wbase,
                                                   const float* __restrict__ bq,
                                                   const float* __restrict__ bk,
                                                   const float* __restrict__ bv,
                                                   float scaleQ,
                                                   bf16_t* __restrict__ QKbase,
                                                   bf16_t* __restrict__ Vt) {
  __shared__ __align__(16) bf16_t sA[2][128 * 32]; // [64][64] swizzled view
  __shared__ __align__(16) bf16_t sB[2][256 * 32]; // [128][64] swizzled view
  const int tid = threadIdx.x;
  const int lane = tid & 63;
  const int w = tid >> 6;            // 0..7
  const int wm = w >> 2, wn = w & 3; // 2 x 4 wave grid
  const int l16 = lane & 15, l4 = lane >> 4;

  // XCD-chunked bijective swizzle (768 = 8 * 96)
  int bid = blockIdx.x;
  int swz = (bid & 7) * 96 + (bid >> 3);
  const int seg = swz >> 8;    // 0,1,2 (256 tiles per seg)
  const int inner = swz & 255;
  const bf16_t* A = Abase + (size_t)seg * NEC;
  const bf16_t* Bw = Wbase + (size_t)seg * WEC;
  const float* bias = seg == 0 ? bq : (seg == 1 ? bk : bv);
  const float scale = seg == 0 ? scaleQ : 1.0f;
  const int bm = inner >> 2, bn = inner & 3; // 64 x 4 tiles
  const int m0 = bm << 7, n0 = bn << 8;

  // staging source mapping (thread-fixed): lane covers LDS linear bytes
  // w*1024 + lane*16 => lrow = w*8 + (lane>>3), slot = lane&7.
  const int sg = (lane & 7) ^ ((lane >> 3) & 7);
  const int mS = 2 * (w * 8 + (lane >> 3)) + (sg >> 2); // tile row 0..127
  const int gS = (sg & 3) * 8;                           // k offset (elems)

  f32x4 acc[4][4] = {};

  auto stage = [&](int bb, int k0) {
    async16(A + (size_t)(m0 + mS) * DMODEL + k0 + gS, &sA[bb][w * 512]);
    async16(Bw + (size_t)(n0 + mS) * DMODEL + k0 + gS, &sB[bb][w * 512]);
    async16(Bw + (size_t)(n0 + 128 + mS) * DMODEL + k0 + gS, &sB[bb][4096 + w * 512]);
  };

  stage(0, 0);
  __syncthreads();
  const int NKT = DMODEL / 32; // 32
  for (int t = 0; t < NKT; ++t) {
    if (t + 1 < NKT) stage((t + 1) & 1, (t + 1) * 32);
    const bf16_t* bA = sA[t & 1];
    const bf16_t* bB = sB[t & 1];
    bf16x8 af[4], bf[4];
#pragma unroll
    for (int f = 0; f < 4; ++f)
      af[f] = *reinterpret_cast<const bf16x8*>(&bA[lds_off(wm * 64 + f * 16 + l16, l4)]);
#pragma unroll
    for (int j = 0; j < 4; ++j)
      bf[j] = *reinterpret_cast<const bf16x8*>(&bB[lds_off(wn * 64 + j * 16 + l16, l4)]);
    __builtin_amdgcn_s_setprio(1);
#pragma unroll
    for (int i = 0; i < 4; ++i)
#pragma unroll
      for (int j = 0; j < 4; ++j)
        acc[i][j] = __builtin_amdgcn_mfma_f32_16x16x32_bf16(af[i], bf[j], acc[i][j], 0, 0, 0);
    __builtin_amdgcn_s_setprio(0);
    __syncthreads();
  }

  // epilogue
  float bj[4];
#pragma unroll
  for (int j = 0; j < 4; ++j) bj[j] = bias[n0 + wn * 64 + j * 16 + l16];

  bf16_t* outQK = QKbase + (size_t)seg * NEC;
#pragma unroll
  for (int i = 0; i < 4; ++i) {
#pragma unroll
    for (int j = 0; j < 4; ++j) {
#pragma unroll
      for (int r = 0; r < 4; ++r) {
        int m = m0 + wm * 64 + i * 16 + l4 * 4 + r;
        int n = n0 + wn * 64 + j * 16 + l16;
        float v = (acc[i][j][r] + bj[j]) * scale;
        int b = m >> 11, s = m & 2047, h = n >> 6, d = n & 63;
        if (seg < 2) {
          outQK[(((size_t)(b * HEADS + h) * SEQ + s) << 6) + d] = (bf16_t)v;
        } else {
          Vt[((size_t)(b * HEADS + h) * DK + d) * SEQ + s] = (bf16_t)v;
        }
      }
    }
  }
}

// ================= final output projection: fp32 out, 128x128 tile =================
// Same 2-phase double-buffered loop as gemm_qkv. 512 blocks = 2/CU, 32KB LDS.
__global__ __launch_bounds__(256, 4) void gemm_out(const bf16_t* __restrict__ A,
                                                   const bf16_t* __restrict__ Bw,
                                                   const float* __restrict__ bias,
                                                   float* __restrict__ Cout) {
  __shared__ __align__(16) bf16_t sA[2][128 * 32]; // [64][64] swizzled view
  __shared__ __align__(16) bf16_t sB[2][128 * 32];
  const int tid = threadIdx.x;
  const int lane = tid & 63;
  const int wv = tid >> 6; // 0..3
  const int l16 = lane & 15, l4 = lane >> 4;

  int bid = blockIdx.x;
  int swz = (bid & 7) * 64 + (bid >> 3); // 512 = 8 * 64
  const int bm = swz >> 3, bn = swz & 7;
  const int m0 = bm << 7, n0 = bn << 7;
  const int wr = (wv >> 1) * 64, wc = (wv & 1) * 64;

  // staging: 2 chunks/thread per tile; chunk c covers LDS bytes
  // c*4096 + wv*1024 + lane*16 => lrow = c*32 + wv*8 + (lane>>3), slot = lane&7
  const int sg = (lane & 7) ^ ((lane >> 3) & 7);
  const int mS = 2 * (wv * 8 + (lane >> 3)) + (sg >> 2); // + c*64
  const int gS = (sg & 3) * 8;

  f32x4 acc[4][4] = {};

  auto stage = [&](int bb, int k0) {
#pragma unroll
    for (int c = 0; c < 2; ++c) {
      async16(A + (size_t)(m0 + c * 64 + mS) * DMODEL + k0 + gS, &sA[bb][c * 2048 + wv * 512]);
      async16(Bw + (size_t)(n0 + c * 64 + mS) * DMODEL + k0 + gS, &sB[bb][c * 2048 + wv * 512]);
    }
  };

  stage(0, 0);
  __syncthreads();
  const int NKT = DMODEL / 32; // 32
  for (int t = 0; t < NKT; ++t) {
    if (t + 1 < NKT) stage((t + 1) & 1, (t + 1) * 32);
    const bf16_t* bA = sA[t & 1];
    const bf16_t* bB = sB[t & 1];
    bf16x8 afrag[4], bfrag[4];
#pragma unroll
    for (int f = 0; f < 4; ++f) {
      afrag[f] = *reinterpret_cast<const bf16x8*>(&bA[lds_off(wr + f * 16 + l16, l4)]);
      bfrag[f] = *reinterpret_cast<const bf16x8*>(&bB[lds_off(wc + f * 16 + l16, l4)]);
    }
    __builtin_amdgcn_s_setprio(1);
#pragma unroll
    for (int i = 0; i < 4; ++i)
#pragma unroll
      for (int j = 0; j < 4; ++j)
        acc[i][j] = __builtin_amdgcn_mfma_f32_16x16x32_bf16(afrag[i], bfrag[j], acc[i][j], 0, 0, 0);
    __builtin_amdgcn_s_setprio(0);
    __syncthreads();
  }

  float bj[4];
#pragma unroll
  for (int j = 0; j < 4; ++j) bj[j] = bias[n0 + wc + j * 16 + l16];

#pragma unroll
  for (int i = 0; i < 4; ++i) {
#pragma unroll
    for (int j = 0; j < 4; ++j) {
#pragma unroll
      for (int r = 0; r < 4; ++r) {
        int m = m0 + wr + i * 16 + l4 * 4 + r;
        int n = n0 + wc + j * 16 + l16;
        Cout[(size_t)m * DMODEL + n] = acc[i][j][r] + bj[j];
      }
    }
  }
}

// ---------------- flash attention (unchanged from R4) ----------------
__device__ __forceinline__ int kvsrc_row(int r) {
  return (r & 32) | (((r >> 3) & 1) << 4) | (((r >> 2) & 1) << 3) |
         (((r >> 4) & 1) << 2) | (r & 3);
}

__global__ __launch_bounds__(512, 2) void attn_kernel(const bf16_t* __restrict__ Q,
                                                      const bf16_t* __restrict__ Kp,
                                                      const bf16_t* __restrict__ Vt,
                                                      bf16_t* __restrict__ AO) {
  __shared__ __align__(16) bf16_t sK[2][64 * 64];
  __shared__ __align__(16) bf16_t sV[2][64 * 64];
  const int tid = threadIdx.x;
  const int lane = tid & 63;
  const int wv = tid >> 6; // 0..7
  const int l16 = lane & 15, l4 = lane >> 4;
  const int sub8 = lane >> 3, c8 = lane & 7;

  const int nq = SEQ / 256; // 8
  int bid = blockIdx.x;
  int swz = (bid & 7) * 64 + (bid >> 3); // 512 blocks, bijective
  const int bh = swz / nq, qt = swz % nq;
  const int b = bh >> 4, h = bh & 15;
  const bf16_t* Qh = Q + (size_t)bh * SEQ * DK;
  const bf16_t* Kh = Kp + (size_t)bh * SEQ * DK;
  const bf16_t* Vh = Vt + (size_t)bh * DK * SEQ;
  const int q0 = qt * 256 + wv * 32;

  bf16x8 aq[2][2];
#pragma unroll
  for (int s = 0; s < 2; ++s)
#pragma unroll
    for (int hf = 0; hf < 2; ++hf)
      aq[s][hf] = *reinterpret_cast<const bf16x8*>(
          &Qh[(size_t)(q0 + s * 16 + l16) * DK + hf * 32 + l4 * 8]);

  bf16x8 ones;
#pragma unroll
  for (int i = 0; i < 8; ++i) ones[i] = (bf16_t)1.0f;

  f32x4 o[2][4] = {};
  f32x4 lacc[2] = {};

  auto stage = [&](int buf, int kv0) {
    int r = wv * 8 + sub8;
    int kvr = kvsrc_row(r);
    int cs = (c8 ^ sub8) << 3;
    async16(Kh + (size_t)(kv0 + kvr) * DK + cs, &sK[buf][wv * 512]);
    async16(Vh + (size_t)r * SEQ + kv0 + cs, &sV[buf][wv * 512]);
  };

  auto compute = [&](int buf) {
    const bf16_t* bK = sK[buf];
    const bf16_t* bV = sV[buf];
    f32x4 sc[2][4] = {};
    __builtin_amdgcn_s_setprio(1);
#pragma unroll
    for (int t = 0; t < 4; ++t) {
      bf16x8 kf0 = *reinterpret_cast<const bf16x8*>(
          &bK[(t * 16 + l16) * 64 + ((l4 ^ (l16 & 7)) << 3)]);
      bf16x8 kf1 = *reinterpret_cast<const bf16x8*>(
          &bK[(t * 16 + l16) * 64 + (((4 + l4) ^ (l16 & 7)) << 3)]);
#pragma unroll
      for (int s = 0; s < 2; ++s) {
        sc[s][t] = __builtin_amdgcn_mfma_f32_16x16x32_bf16(kf0, aq[s][0], sc[s][t], 0, 0, 0);
        sc[s][t] = __builtin_amdgcn_mfma_f32_16x16x32_bf16(kf1, aq[s][1], sc[s][t], 0, 0, 0);
      }
    }
    __builtin_amdgcn_s_setprio(0);
    bf16x8 pa[2][2];
#pragma unroll
    for (int s = 0; s < 2; ++s) {
#pragma unroll
      for (int t = 0; t < 4; ++t) {
#pragma unroll
        for (int j = 0; j < 4; ++j) {
          pa[s][t >> 1][(t & 1) * 4 + j] = (bf16_t)__builtin_amdgcn_exp2f(sc[s][t][j]);
        }
      }
    }
    __builtin_amdgcn_s_setprio(1);
#pragma unroll
    for (int nb = 0; nb < 4; ++nb) {
      bf16x8 vf0 = *reinterpret_cast<const bf16x8*>(
          &bV[(nb * 16 + l16) * 64 + ((l4 ^ (l16 & 7)) << 3)]);
      bf16x8 vf1 = *reinterpret_cast<const bf16x8*>(
          &bV[(nb * 16 + l16) * 64 + (((4 + l4) ^ (l16 & 7)) << 3)]);
#pragma unroll
      for (int s = 0; s < 2; ++s) {
        o[s][nb] = __builtin_amdgcn_mfma_f32_16x16x32_bf16(pa[s][0], vf0, o[s][nb], 0, 0, 0);
        o[s][nb] = __builtin_amdgcn_mfma_f32_16x16x32_bf16(pa[s][1], vf1, o[s][nb], 0, 0, 0);
      }
    }
#pragma unroll
    for (int s = 0; s < 2; ++s) {
      lacc[s] = __builtin_amdgcn_mfma_f32_16x16x32_bf16(pa[s][0], ones, lacc[s], 0, 0, 0);
      lacc[s] = __builtin_amdgcn_mfma_f32_16x16x32_bf16(pa[s][1], ones, lacc[s], 0, 0, 0);
    }
    __builtin_amdgcn_s_setprio(0);
  };

  stage(0, 0);
  __syncthreads();
  const int NT = SEQ / 64; // 32
  for (int it = 0; it < NT; ++it) {
    if (it + 1 < NT) stage((it + 1) & 1, (it + 1) * 64);
    compute(it & 1);
    __syncthreads();
  }

#pragma unroll
  for (int s = 0; s < 2; ++s) {
#pragma unroll
    for (int j = 0; j < 4; ++j) {
      float inv = 1.0f / lacc[s][j];
      int qrow = q0 + s * 16 + l4 * 4 + j;
#pragma unroll
      for (int nb = 0; nb < 4; ++nb)
        AO[((size_t)(b * SEQ + qrow)) * DMODEL + h * DK + nb * 16 + l16] =
            (bf16_t)(o[s][nb][j] * inv);
    }
  }
}

// ---------------- launcher ----------------
extern "C" void kernel_launch(void* const* d_in, const int* in_sizes, int n_in,
                              void* d_out, int out_size, void* d_ws, size_t ws_size,
                              hipStream_t stream) {
  const float* query = (const float*)d_in[0];
  const float* key_i = (const float*)d_in[1];
  const float* value = (const float*)d_in[2];
  const float* Wq = (const float*)d_in[3];
  const float* bq = (const float*)d_in[4];
  const float* Wk = (const float*)d_in[5];
  const float* bk = (const float*)d_in[6];
  const float* Wv = (const float*)d_in[7];
  const float* bv = (const float*)d_in[8];
  const float* Wo = (const float*)d_in[9];
  const float* bo = (const float*)d_in[10];
  float* out = (float*)d_out;

  bf16_t* qb = (bf16_t*)d_ws;       // qb|kb|vb contiguous (A segments)
  bf16_t* wqb = qb + 3 * NEC;       // wqb|wkb|wvb contiguous (W segments)
  bf16_t* wob = wqb + 3 * WEC;
  bf16_t* Qp = wob + WEC;           // Qp|Kp contiguous (QK output segments)
  bf16_t* Kp = Qp + NEC;
  bf16_t* Vt = Kp + NEC;
  bf16_t* AO = Vt + NEC;
  // workspace: (7*NEC + 4*WEC)*2 = 120 MiB

  size_t totE = 3 * NEC + 4 * WEC; // 28M elems
  cast_all<<<dim3((unsigned)(totE / 8 / 256)), dim3(256), 0, stream>>>(
      query, key_i, value, Wq, Wk, Wv, Wo, qb);

  const float cexp = 0.18033688f; // log2(e)/8, folded into Q projection
  gemm_qkv<<<dim3(768), dim3(512), 0, stream>>>(qb, wqb, bq, bk, bv, cexp, Qp, Vt);

  attn_kernel<<<dim3(4 * HEADS * (SEQ / 256)), 512, 0, stream>>>(Qp, Kp, Vt, AO);

  gemm_out<<<dim3(512), dim3(256), 0, stream>>>(AO, wob, bo, out);
}

// Round 9
// 179.805 us; speedup vs baseline: 1.3632x; 1.2121x over previous
//
#include <hip/hip_runtime.h>
#include <cstdint>
#include <cstddef>

typedef __bf16 bf16_t;
typedef __bf16 bf16x8 __attribute__((ext_vector_type(8)));
typedef __bf16 bf16x4 __attribute__((ext_vector_type(4)));
typedef float f32x4 __attribute__((ext_vector_type(4)));

static constexpr int SEQ = 2048;
static constexpr int DMODEL = 1024;
static constexpr int HEADS = 16;
static constexpr int DK = 64;
static constexpr int MROWS = 4 * SEQ;               // B*S = 8192
static constexpr size_t NEC = (size_t)MROWS * DMODEL; // 8M elems
static constexpr size_t WEC = (size_t)DMODEL * DMODEL; // 1M elems

// ---------------- fused fp32 -> bf16 cast for all 7 arrays ----------------
__global__ __launch_bounds__(256) void cast_all(const float* __restrict__ q,
                                                const float* __restrict__ k,
                                                const float* __restrict__ v,
                                                const float* __restrict__ wq,
                                                const float* __restrict__ wk,
                                                const float* __restrict__ wv,
                                                const float* __restrict__ wo,
                                                bf16_t* __restrict__ out) {
  size_t i = (size_t)blockIdx.x * 256 + threadIdx.x;
  size_t e = i * 8;
  const float* src;
  size_t off;
  if (e < NEC) { src = q; off = e; }
  else if (e < 2 * NEC) { src = k; off = e - NEC; }
  else if (e < 3 * NEC) { src = v; off = e - 2 * NEC; }
  else if (e < 3 * NEC + WEC) { src = wq; off = e - 3 * NEC; }
  else if (e < 3 * NEC + 2 * WEC) { src = wk; off = e - 3 * NEC - WEC; }
  else if (e < 3 * NEC + 3 * WEC) { src = wv; off = e - 3 * NEC - 2 * WEC; }
  else { src = wo; off = e - 3 * NEC - 3 * WEC; }
  const float4* p = reinterpret_cast<const float4*>(src + off);
  float4 a = p[0], b = p[1];
  bf16x8 o;
  o[0] = (bf16_t)a.x; o[1] = (bf16_t)a.y; o[2] = (bf16_t)a.z; o[3] = (bf16_t)a.w;
  o[4] = (bf16_t)b.x; o[5] = (bf16_t)b.y; o[6] = (bf16_t)b.z; o[7] = (bf16_t)b.w;
  *(reinterpret_cast<bf16x8*>(out + e)) = o;
}

// ---------------- async global -> LDS, 16B per lane ----------------
__device__ __forceinline__ void async16(const bf16_t* g, bf16_t* l) {
  __builtin_amdgcn_global_load_lds((const __attribute__((address_space(1))) void*)g,
                                   (__attribute__((address_space(3))) void*)l,
                                   16, 0, 0);
}

// Conflict-free LDS addressing for [rows][32]-elem bf16 K-tiles (main loop):
// view as [rows/2][64 elems], slot s3 = ((m&1)<<2)|kgroup, s3 ^= (lrow&7).
__device__ __forceinline__ int lds_off(int m, int l4) {
  int lr = m >> 1;
  return lr * 64 + (((((m & 1) << 2) | l4) ^ (lr & 7)) << 3);
}

// ================= merged Q/K/V projection GEMM, 128x256 tile =================
// Main loop unchanged from R8 (2-phase dbuf, one barrier/K-step, swizzled LDS).
// NEW: epilogue repacks acc through a wave-local LDS patch (no barriers) so all
// global stores are coalesced 16B/lane vector stores:
//  - Q/K: each wave owns one head (d 0..63) x 64 s-rows -> 128B-contiguous rows.
//  - V  : pack 4 consecutive-s acc elems -> ds_write_b64, read 16B s-chunks.
__global__ __launch_bounds__(512, 4) void gemm_qkv(const bf16_t* __restrict__ Abase,
                                                   const bf16_t* __restrict__ Wbase,
                                                   const float* __restrict__ bq,
                                                   const float* __restrict__ bk,
                                                   const float* __restrict__ bv,
                                                   float scaleQ,
                                                   bf16_t* __restrict__ QKbase,
                                                   bf16_t* __restrict__ Vt) {
  __shared__ __align__(16) bf16_t smem[24576]; // 48KB: sA[2][4096] | sB[2][8192]
  bf16_t* sAb = smem;
  bf16_t* sBb = smem + 8192;
  const int tid = threadIdx.x;
  const int lane = tid & 63;
  const int w = tid >> 6;            // 0..7
  const int wm = w >> 2, wn = w & 3; // 2 x 4 wave grid
  const int l16 = lane & 15, l4 = lane >> 4;

  // XCD-chunked bijective swizzle (768 = 8 * 96)
  int bid = blockIdx.x;
  int swz = (bid & 7) * 96 + (bid >> 3);
  const int seg = swz >> 8;    // 0,1,2 (256 tiles per seg)
  const int inner = swz & 255;
  const bf16_t* A = Abase + (size_t)seg * NEC;
  const bf16_t* Bw = Wbase + (size_t)seg * WEC;
  const float* bias = seg == 0 ? bq : (seg == 1 ? bk : bv);
  const float scale = seg == 0 ? scaleQ : 1.0f;
  const int bm = inner >> 2, bn = inner & 3; // 64 x 4 tiles
  const int m0 = bm << 7, n0 = bn << 8;

  // staging source mapping (thread-fixed)
  const int sg = (lane & 7) ^ ((lane >> 3) & 7);
  const int mS = 2 * (w * 8 + (lane >> 3)) + (sg >> 2); // tile row 0..127
  const int gS = (sg & 3) * 8;                           // k offset (elems)

  f32x4 acc[4][4] = {};

  auto stage = [&](int bb, int k0) {
    async16(A + (size_t)(m0 + mS) * DMODEL + k0 + gS, &sAb[bb * 4096 + w * 512]);
    async16(Bw + (size_t)(n0 + mS) * DMODEL + k0 + gS, &sBb[bb * 8192 + w * 512]);
    async16(Bw + (size_t)(n0 + 128 + mS) * DMODEL + k0 + gS, &sBb[bb * 8192 + 4096 + w * 512]);
  };

  stage(0, 0);
  __syncthreads();
  const int NKT = DMODEL / 32; // 32
  for (int t = 0; t < NKT; ++t) {
    if (t + 1 < NKT) stage((t + 1) & 1, (t + 1) * 32);
    const bf16_t* bA = &sAb[(t & 1) * 4096];
    const bf16_t* bB = &sBb[(t & 1) * 8192];
    bf16x8 af[4], bf[4];
#pragma unroll
    for (int f = 0; f < 4; ++f)
      af[f] = *reinterpret_cast<const bf16x8*>(&bA[lds_off(wm * 64 + f * 16 + l16, l4)]);
#pragma unroll
    for (int j = 0; j < 4; ++j)
      bf[j] = *reinterpret_cast<const bf16x8*>(&bB[lds_off(wn * 64 + j * 16 + l16, l4)]);
    __builtin_amdgcn_s_setprio(1);
#pragma unroll
    for (int i = 0; i < 4; ++i)
#pragma unroll
      for (int j = 0; j < 4; ++j)
        acc[i][j] = __builtin_amdgcn_mfma_f32_16x16x32_bf16(af[i], bf[j], acc[i][j], 0, 0, 0);
    __builtin_amdgcn_s_setprio(0);
    __syncthreads();
  }
  // After the final barrier every wave's LDS reads are done -> smem reusable.
  // Epilogue works in wave-local patches only => no further barriers needed.

  float bj[4];
#pragma unroll
  for (int j = 0; j < 4; ++j) bj[j] = bias[n0 + wn * 64 + j * 16 + l16];

  const int hglob = bn * 4 + wn;           // each wave owns exactly one head
  bf16_t* patch = smem + w * 3072;         // 6KB per wave

  if (seg < 2) {
    bf16_t* outQK = QKbase + (size_t)seg * NEC;
#pragma unroll
    for (int h2 = 0; h2 < 2; ++h2) {
      // write half-tile [32 m][64 d] into [32][72] padded patch
#pragma unroll
      for (int ii = 0; ii < 2; ++ii) {
        int i = h2 * 2 + ii;
#pragma unroll
        for (int j = 0; j < 4; ++j) {
#pragma unroll
          for (int r = 0; r < 4; ++r) {
            float v = (acc[i][j][r] + bj[j]) * scale;
            patch[(ii * 16 + l4 * 4 + r) * 72 + j * 16 + l16] = (bf16_t)v;
          }
        }
      }
      // read back 16B/lane, fully-coalesced 1KB stores
#pragma unroll
      for (int kk = 0; kk < 4; ++kk) {
        int row = kk * 8 + (lane >> 3);
        int doff = (lane & 7) * 8;
        bf16x8 ch = *reinterpret_cast<const bf16x8*>(&patch[row * 72 + doff]);
        int m = m0 + wm * 64 + h2 * 32 + row;
        int b = m >> 11, s = m & 2047;
        *reinterpret_cast<bf16x8*>(
            &outQK[(((size_t)(b * HEADS + hglob) * SEQ + s) << 6) + doff]) = ch;
      }
    }
  } else {
    // V: transpose to [B,H,dk,S] via [64 d][48] padded patch (96B rows)
#pragma unroll
    for (int h2 = 0; h2 < 2; ++h2) {
#pragma unroll
      for (int ii = 0; ii < 2; ++ii) {
        int i = h2 * 2 + ii;
#pragma unroll
        for (int j = 0; j < 4; ++j) {
          bf16x4 pk;
#pragma unroll
          for (int r = 0; r < 4; ++r) pk[r] = (bf16_t)(acc[i][j][r] + bj[j]);
          *reinterpret_cast<bf16x4*>(
              &patch[(j * 16 + l16) * 48 + ii * 16 + l4 * 4]) = pk;
        }
      }
#pragma unroll
      for (int kk = 0; kk < 4; ++kk) {
        int d = kk * 16 + (lane >> 2);
        int soff = (lane & 3) * 8;
        bf16x8 ch = *reinterpret_cast<const bf16x8*>(&patch[d * 48 + soff]);
        int m = m0 + wm * 64 + h2 * 32; // base s of this half (32-row span)
        int b = m >> 11, s = (m & 2047) + soff;
        *reinterpret_cast<bf16x8*>(
            &Vt[((size_t)(b * HEADS + hglob) * DK + d) * SEQ + s]) = ch;
      }
    }
  }
}

// ================= final output projection: fp32 out, 128x128 tile =================
__global__ __launch_bounds__(256, 4) void gemm_out(const bf16_t* __restrict__ A,
                                                   const bf16_t* __restrict__ Bw,
                                                   const float* __restrict__ bias,
                                                   float* __restrict__ Cout) {
  __shared__ __align__(16) bf16_t sA[2][128 * 32]; // [64][64] swizzled view
  __shared__ __align__(16) bf16_t sB[2][128 * 32];
  const int tid = threadIdx.x;
  const int lane = tid & 63;
  const int wv = tid >> 6; // 0..3
  const int l16 = lane & 15, l4 = lane >> 4;

  int bid = blockIdx.x;
  int swz = (bid & 7) * 64 + (bid >> 3); // 512 = 8 * 64
  const int bm = swz >> 3, bn = swz & 7;
  const int m0 = bm << 7, n0 = bn << 7;
  const int wr = (wv >> 1) * 64, wc = (wv & 1) * 64;

  const int sg = (lane & 7) ^ ((lane >> 3) & 7);
  const int mS = 2 * (wv * 8 + (lane >> 3)) + (sg >> 2); // + c*64
  const int gS = (sg & 3) * 8;

  f32x4 acc[4][4] = {};

  auto stage = [&](int bb, int k0) {
#pragma unroll
    for (int c = 0; c < 2; ++c) {
      async16(A + (size_t)(m0 + c * 64 + mS) * DMODEL + k0 + gS, &sA[bb][c * 2048 + wv * 512]);
      async16(Bw + (size_t)(n0 + c * 64 + mS) * DMODEL + k0 + gS, &sB[bb][c * 2048 + wv * 512]);
    }
  };

  stage(0, 0);
  __syncthreads();
  const int NKT = DMODEL / 32; // 32
  for (int t = 0; t < NKT; ++t) {
    if (t + 1 < NKT) stage((t + 1) & 1, (t + 1) * 32);
    const bf16_t* bA = sA[t & 1];
    const bf16_t* bB = sB[t & 1];
    bf16x8 afrag[4], bfrag[4];
#pragma unroll
    for (int f = 0; f < 4; ++f) {
      afrag[f] = *reinterpret_cast<const bf16x8*>(&bA[lds_off(wr + f * 16 + l16, l4)]);
      bfrag[f] = *reinterpret_cast<const bf16x8*>(&bB[lds_off(wc + f * 16 + l16, l4)]);
    }
    __builtin_amdgcn_s_setprio(1);
#pragma unroll
    for (int i = 0; i < 4; ++i)
#pragma unroll
      for (int j = 0; j < 4; ++j)
        acc[i][j] = __builtin_amdgcn_mfma_f32_16x16x32_bf16(afrag[i], bfrag[j], acc[i][j], 0, 0, 0);
    __builtin_amdgcn_s_setprio(0);
    __syncthreads();
  }

  float bj[4];
#pragma unroll
  for (int j = 0; j < 4; ++j) bj[j] = bias[n0 + wc + j * 16 + l16];

#pragma unroll
  for (int i = 0; i < 4; ++i) {
#pragma unroll
    for (int j = 0; j < 4; ++j) {
#pragma unroll
      for (int r = 0; r < 4; ++r) {
        int m = m0 + wr + i * 16 + l4 * 4 + r;
        int n = n0 + wc + j * 16 + l16;
        Cout[(size_t)m * DMODEL + n] = acc[i][j][r] + bj[j];
      }
    }
  }
}

// ---------------- flash attention (unchanged from R4) ----------------
__device__ __forceinline__ int kvsrc_row(int r) {
  return (r & 32) | (((r >> 3) & 1) << 4) | (((r >> 2) & 1) << 3) |
         (((r >> 4) & 1) << 2) | (r & 3);
}

__global__ __launch_bounds__(512, 2) void attn_kernel(const bf16_t* __restrict__ Q,
                                                      const bf16_t* __restrict__ Kp,
                                                      const bf16_t* __restrict__ Vt,
                                                      bf16_t* __restrict__ AO) {
  __shared__ __align__(16) bf16_t sK[2][64 * 64];
  __shared__ __align__(16) bf16_t sV[2][64 * 64];
  const int tid = threadIdx.x;
  const int lane = tid & 63;
  const int wv = tid >> 6; // 0..7
  const int l16 = lane & 15, l4 = lane >> 4;
  const int sub8 = lane >> 3, c8 = lane & 7;

  const int nq = SEQ / 256; // 8
  int bid = blockIdx.x;
  int swz = (bid & 7) * 64 + (bid >> 3); // 512 blocks, bijective
  const int bh = swz / nq, qt = swz % nq;
  const int b = bh >> 4, h = bh & 15;
  const bf16_t* Qh = Q + (size_t)bh * SEQ * DK;
  const bf16_t* Kh = Kp + (size_t)bh * SEQ * DK;
  const bf16_t* Vh = Vt + (size_t)bh * DK * SEQ;
  const int q0 = qt * 256 + wv * 32;

  bf16x8 aq[2][2];
#pragma unroll
  for (int s = 0; s < 2; ++s)
#pragma unroll
    for (int hf = 0; hf < 2; ++hf)
      aq[s][hf] = *reinterpret_cast<const bf16x8*>(
          &Qh[(size_t)(q0 + s * 16 + l16) * DK + hf * 32 + l4 * 8]);

  bf16x8 ones;
#pragma unroll
  for (int i = 0; i < 8; ++i) ones[i] = (bf16_t)1.0f;

  f32x4 o[2][4] = {};
  f32x4 lacc[2] = {};

  auto stage = [&](int buf, int kv0) {
    int r = wv * 8 + sub8;
    int kvr = kvsrc_row(r);
    int cs = (c8 ^ sub8) << 3;
    async16(Kh + (size_t)(kv0 + kvr) * DK + cs, &sK[buf][wv * 512]);
    async16(Vh + (size_t)r * SEQ + kv0 + cs, &sV[buf][wv * 512]);
  };

  auto compute = [&](int buf) {
    const bf16_t* bK = sK[buf];
    const bf16_t* bV = sV[buf];
    f32x4 sc[2][4] = {};
    __builtin_amdgcn_s_setprio(1);
#pragma unroll
    for (int t = 0; t < 4; ++t) {
      bf16x8 kf0 = *reinterpret_cast<const bf16x8*>(
          &bK[(t * 16 + l16) * 64 + ((l4 ^ (l16 & 7)) << 3)]);
      bf16x8 kf1 = *reinterpret_cast<const bf16x8*>(
          &bK[(t * 16 + l16) * 64 + (((4 + l4) ^ (l16 & 7)) << 3)]);
#pragma unroll
      for (int s = 0; s < 2; ++s) {
        sc[s][t] = __builtin_amdgcn_mfma_f32_16x16x32_bf16(kf0, aq[s][0], sc[s][t], 0, 0, 0);
        sc[s][t] = __builtin_amdgcn_mfma_f32_16x16x32_bf16(kf1, aq[s][1], sc[s][t], 0, 0, 0);
      }
    }
    __builtin_amdgcn_s_setprio(0);
    bf16x8 pa[2][2];
#pragma unroll
    for (int s = 0; s < 2; ++s) {
#pragma unroll
      for (int t = 0; t < 4; ++t) {
#pragma unroll
        for (int j = 0; j < 4; ++j) {
          pa[s][t >> 1][(t & 1) * 4 + j] = (bf16_t)__builtin_amdgcn_exp2f(sc[s][t][j]);
        }
      }
    }
    __builtin_amdgcn_s_setprio(1);
#pragma unroll
    for (int nb = 0; nb < 4; ++nb) {
      bf16x8 vf0 = *reinterpret_cast<const bf16x8*>(
          &bV[(nb * 16 + l16) * 64 + ((l4 ^ (l16 & 7)) << 3)]);
      bf16x8 vf1 = *reinterpret_cast<const bf16x8*>(
          &bV[(nb * 16 + l16) * 64 + (((4 + l4) ^ (l16 & 7)) << 3)]);
#pragma unroll
      for (int s = 0; s < 2; ++s) {
        o[s][nb] = __builtin_amdgcn_mfma_f32_16x16x32_bf16(pa[s][0], vf0, o[s][nb], 0, 0, 0);
        o[s][nb] = __builtin_amdgcn_mfma_f32_16x16x32_bf16(pa[s][1], vf1, o[s][nb], 0, 0, 0);
      }
    }
#pragma unroll
    for (int s = 0; s < 2; ++s) {
      lacc[s] = __builtin_amdgcn_mfma_f32_16x16x32_bf16(pa[s][0], ones, lacc[s], 0, 0, 0);
      lacc[s] = __builtin_amdgcn_mfma_f32_16x16x32_bf16(pa[s][1], ones, lacc[s], 0, 0, 0);
    }
    __builtin_amdgcn_s_setprio(0);
  };

  stage(0, 0);
  __syncthreads();
  const int NT = SEQ / 64; // 32
  for (int it = 0; it < NT; ++it) {
    if (it + 1 < NT) stage((it + 1) & 1, (it + 1) * 64);
    compute(it & 1);
    __syncthreads();
  }

#pragma unroll
  for (int s = 0; s < 2; ++s) {
#pragma unroll
    for (int j = 0; j < 4; ++j) {
      float inv = 1.0f / lacc[s][j];
      int qrow = q0 + s * 16 + l4 * 4 + j;
#pragma unroll
      for (int nb = 0; nb < 4; ++nb)
        AO[((size_t)(b * SEQ + qrow)) * DMODEL + h * DK + nb * 16 + l16] =
            (bf16_t)(o[s][nb][j] * inv);
    }
  }
}

// ---------------- launcher ----------------
extern "C" void kernel_launch(void* const* d_in, const int* in_sizes, int n_in,
                              void* d_out, int out_size, void* d_ws, size_t ws_size,
                              hipStream_t stream) {
  const float* query = (const float*)d_in[0];
  const float* key_i = (const float*)d_in[1];
  const float* value = (const float*)d_in[2];
  const float* Wq = (const float*)d_in[3];
  const float* bq = (const float*)d_in[4];
  const float* Wk = (const float*)d_in[5];
  const float* bk = (const float*)d_in[6];
  const float* Wv = (const float*)d_in[7];
  const float* bv = (const float*)d_in[8];
  const float* Wo = (const float*)d_in[9];
  const float* bo = (const float*)d_in[10];
  float* out = (float*)d_out;

  bf16_t* qb = (bf16_t*)d_ws;       // qb|kb|vb contiguous (A segments)
  bf16_t* wqb = qb + 3 * NEC;       // wqb|wkb|wvb contiguous (W segments)
  bf16_t* wob = wqb + 3 * WEC;
  bf16_t* Qp = wob + WEC;           // Qp|Kp contiguous (QK output segments)
  bf16_t* Kp = Qp + NEC;
  bf16_t* Vt = Kp + NEC;
  bf16_t* AO = Vt + NEC;
  // workspace: (7*NEC + 4*WEC)*2 = 120 MiB

  size_t totE = 3 * NEC + 4 * WEC; // 28M elems
  cast_all<<<dim3((unsigned)(totE / 8 / 256)), dim3(256), 0, stream>>>(
      query, key_i, value, Wq, Wk, Wv, Wo, qb);

  const float cexp = 0.18033688f; // log2(e)/8, folded into Q projection
  gemm_qkv<<<dim3(768), dim3(512), 0, stream>>>(qb, wqb, bq, bk, bv, cexp, Qp, Vt);

  attn_kernel<<<dim3(4 * HEADS * (SEQ / 256)), 512, 0, stream>>>(Qp, Kp, Vt, AO);

  gemm_out<<<dim3(512), dim3(256), 0, stream>>>(AO, wob, bo, out);
}

// Round 10
// 168.278 us; speedup vs baseline: 1.4565x; 1.0685x over previous
//
#include <hip/hip_runtime.h>
#include <cstdint>
#include <cstddef>

typedef __bf16 bf16_t;
typedef __bf16 bf16x8 __attribute__((ext_vector_type(8)));
typedef __bf16 bf16x4 __attribute__((ext_vector_type(4)));
typedef float f32x4 __attribute__((ext_vector_type(4)));

static constexpr int SEQ = 2048;
static constexpr int DMODEL = 1024;
static constexpr int HEADS = 16;
static constexpr int DK = 64;
static constexpr int MROWS = 4 * SEQ;               // B*S = 8192
static constexpr size_t NEC = (size_t)MROWS * DMODEL; // 8M elems
static constexpr size_t WEC = (size_t)DMODEL * DMODEL; // 1M elems

// ---------------- fp32 -> bf16 cast for the 4 weight matrices only ----------------
__global__ __launch_bounds__(256) void cast_w(const float* __restrict__ wq,
                                              const float* __restrict__ wk,
                                              const float* __restrict__ wv,
                                              const float* __restrict__ wo,
                                              bf16_t* __restrict__ out) {
  size_t i = (size_t)blockIdx.x * 256 + threadIdx.x;
  size_t e = i * 8;
  const float* src;
  size_t off;
  if (e < WEC) { src = wq; off = e; }
  else if (e < 2 * WEC) { src = wk; off = e - WEC; }
  else if (e < 3 * WEC) { src = wv; off = e - 2 * WEC; }
  else { src = wo; off = e - 3 * WEC; }
  const float4* p = reinterpret_cast<const float4*>(src + off);
  float4 a = p[0], b = p[1];
  bf16x8 o;
  o[0] = (bf16_t)a.x; o[1] = (bf16_t)a.y; o[2] = (bf16_t)a.z; o[3] = (bf16_t)a.w;
  o[4] = (bf16_t)b.x; o[5] = (bf16_t)b.y; o[6] = (bf16_t)b.z; o[7] = (bf16_t)b.w;
  *(reinterpret_cast<bf16x8*>(out + e)) = o;
}

// ---------------- async global -> LDS, 16B per lane ----------------
__device__ __forceinline__ void async16(const bf16_t* g, bf16_t* l) {
  __builtin_amdgcn_global_load_lds((const __attribute__((address_space(1))) void*)g,
                                   (__attribute__((address_space(3))) void*)l,
                                   16, 0, 0);
}

// Conflict-free LDS addressing for [rows][32]-elem bf16 K-tiles (main loop):
// view as [rows/2][64 elems], slot s3 = ((m&1)<<2)|kgroup, s3 ^= (lrow&7).
__device__ __forceinline__ int lds_off(int m, int l4) {
  int lr = m >> 1;
  return lr * 64 + (((((m & 1) << 2) | l4) ^ (lr & 7)) << 3);
}

// ================= merged Q/K/V projection GEMM, 128x256 tile =================
// A (activations) staged DIRECTLY FROM FP32 INPUTS via reg-staging (T14 split:
// fp32 loads issued at iter top, cvt+ds_write after the MFMA cluster so HBM
// latency hides under compute). B (weights, pre-cast bf16) via global_load_lds.
// Same swizzled LDS layout both paths; same 2-phase dbuf 1-barrier loop (R8);
// same coalesced LDS-repack epilogue (R9).
__global__ __launch_bounds__(512, 4) void gemm_qkv(const float* __restrict__ Aq,
                                                   const float* __restrict__ Ak,
                                                   const float* __restrict__ Av,
                                                   const bf16_t* __restrict__ Wbase,
                                                   const float* __restrict__ bq,
                                                   const float* __restrict__ bk,
                                                   const float* __restrict__ bv,
                                                   float scaleQ,
                                                   bf16_t* __restrict__ QKbase,
                                                   bf16_t* __restrict__ Vt) {
  __shared__ __align__(16) bf16_t smem[24576]; // 48KB: sA[2][4096] | sB[2][8192]
  bf16_t* sAb = smem;
  bf16_t* sBb = smem + 8192;
  const int tid = threadIdx.x;
  const int lane = tid & 63;
  const int w = tid >> 6;            // 0..7
  const int wm = w >> 2, wn = w & 3; // 2 x 4 wave grid
  const int l16 = lane & 15, l4 = lane >> 4;

  // XCD-chunked bijective swizzle (768 = 8 * 96)
  int bid = blockIdx.x;
  int swz = (bid & 7) * 96 + (bid >> 3);
  const int seg = swz >> 8;    // 0,1,2 (256 tiles per seg)
  const int inner = swz & 255;
  const float* Afp = seg == 0 ? Aq : (seg == 1 ? Ak : Av);
  const bf16_t* Bw = Wbase + (size_t)seg * WEC;
  const float* bias = seg == 0 ? bq : (seg == 1 ? bk : bv);
  const float scale = seg == 0 ? scaleQ : 1.0f;
  const int bm = inner >> 2, bn = inner & 3; // 64 x 4 tiles
  const int m0 = bm << 7, n0 = bn << 8;

  // staging source mapping (thread-fixed): lane covers LDS linear bytes
  // w*1024 + lane*16 (elems: w*512 + lane*8)
  const int sg = (lane & 7) ^ ((lane >> 3) & 7);
  const int mS = 2 * (w * 8 + (lane >> 3)) + (sg >> 2); // tile row 0..127
  const int gS = (sg & 3) * 8;                           // k offset (elems)

  f32x4 acc[4][4] = {};
  float4 ra0, ra1; // in-flight fp32 A chunk (8 elems)

  auto loadA = [&](int k0) {
    const float* p = Afp + (size_t)(m0 + mS) * DMODEL + k0 + gS;
    ra0 = *reinterpret_cast<const float4*>(p);
    ra1 = *reinterpret_cast<const float4*>(p + 4);
  };
  auto writeA = [&](int bb) {
    bf16x8 o;
    o[0] = (bf16_t)ra0.x; o[1] = (bf16_t)ra0.y; o[2] = (bf16_t)ra0.z; o[3] = (bf16_t)ra0.w;
    o[4] = (bf16_t)ra1.x; o[5] = (bf16_t)ra1.y; o[6] = (bf16_t)ra1.z; o[7] = (bf16_t)ra1.w;
    *reinterpret_cast<bf16x8*>(&sAb[bb * 4096 + w * 512 + lane * 8]) = o;
  };
  auto stageB = [&](int bb, int k0) {
    async16(Bw + (size_t)(n0 + mS) * DMODEL + k0 + gS, &sBb[bb * 8192 + w * 512]);
    async16(Bw + (size_t)(n0 + 128 + mS) * DMODEL + k0 + gS, &sBb[bb * 8192 + 4096 + w * 512]);
  };

  loadA(0);
  stageB(0, 0);
  writeA(0);
  __syncthreads(); // drains async16 (vmcnt0) + ds_write (lgkm)
  const int NKT = DMODEL / 32; // 32
  for (int t = 0; t < NKT; ++t) {
    if (t + 1 < NKT) {
      loadA((t + 1) * 32);        // issue early: latency hides under MFMA
      stageB((t + 1) & 1, (t + 1) * 32);
    }
    const bf16_t* bA = &sAb[(t & 1) * 4096];
    const bf16_t* bB = &sBb[(t & 1) * 8192];
    bf16x8 af[4], bf[4];
#pragma unroll
    for (int f = 0; f < 4; ++f)
      af[f] = *reinterpret_cast<const bf16x8*>(&bA[lds_off(wm * 64 + f * 16 + l16, l4)]);
#pragma unroll
    for (int j = 0; j < 4; ++j)
      bf[j] = *reinterpret_cast<const bf16x8*>(&bB[lds_off(wn * 64 + j * 16 + l16, l4)]);
    __builtin_amdgcn_s_setprio(1);
#pragma unroll
    for (int i = 0; i < 4; ++i)
#pragma unroll
      for (int j = 0; j < 4; ++j)
        acc[i][j] = __builtin_amdgcn_mfma_f32_16x16x32_bf16(af[i], bf[j], acc[i][j], 0, 0, 0);
    __builtin_amdgcn_s_setprio(0);
    if (t + 1 < NKT) writeA((t + 1) & 1); // cvt + ds_write (loads landed under MFMA)
    __syncthreads();
  }
  // Epilogue: wave-local LDS repack (no barriers; smem free after final barrier)

  float bj[4];
#pragma unroll
  for (int j = 0; j < 4; ++j) bj[j] = bias[n0 + wn * 64 + j * 16 + l16];

  const int hglob = bn * 4 + wn;           // each wave owns exactly one head
  bf16_t* patch = smem + w * 3072;         // 6KB per wave

  if (seg < 2) {
    bf16_t* outQK = QKbase + (size_t)seg * NEC;
#pragma unroll
    for (int h2 = 0; h2 < 2; ++h2) {
#pragma unroll
      for (int ii = 0; ii < 2; ++ii) {
        int i = h2 * 2 + ii;
#pragma unroll
        for (int j = 0; j < 4; ++j) {
#pragma unroll
          for (int r = 0; r < 4; ++r) {
            float v = (acc[i][j][r] + bj[j]) * scale;
            patch[(ii * 16 + l4 * 4 + r) * 72 + j * 16 + l16] = (bf16_t)v;
          }
        }
      }
#pragma unroll
      for (int kk = 0; kk < 4; ++kk) {
        int row = kk * 8 + (lane >> 3);
        int doff = (lane & 7) * 8;
        bf16x8 ch = *reinterpret_cast<const bf16x8*>(&patch[row * 72 + doff]);
        int m = m0 + wm * 64 + h2 * 32 + row;
        int b = m >> 11, s = m & 2047;
        *reinterpret_cast<bf16x8*>(
            &outQK[(((size_t)(b * HEADS + hglob) * SEQ + s) << 6) + doff]) = ch;
      }
    }
  } else {
    // V: transpose to [B,H,dk,S] via [64 d][48] padded patch (96B rows)
#pragma unroll
    for (int h2 = 0; h2 < 2; ++h2) {
#pragma unroll
      for (int ii = 0; ii < 2; ++ii) {
        int i = h2 * 2 + ii;
#pragma unroll
        for (int j = 0; j < 4; ++j) {
          bf16x4 pk;
#pragma unroll
          for (int r = 0; r < 4; ++r) pk[r] = (bf16_t)(acc[i][j][r] + bj[j]);
          *reinterpret_cast<bf16x4*>(
              &patch[(j * 16 + l16) * 48 + ii * 16 + l4 * 4]) = pk;
        }
      }
#pragma unroll
      for (int kk = 0; kk < 4; ++kk) {
        int d = kk * 16 + (lane >> 2);
        int soff = (lane & 3) * 8;
        bf16x8 ch = *reinterpret_cast<const bf16x8*>(&patch[d * 48 + soff]);
        int m = m0 + wm * 64 + h2 * 32;
        int b = m >> 11, s = (m & 2047) + soff;
        *reinterpret_cast<bf16x8*>(
            &Vt[((size_t)(b * HEADS + hglob) * DK + d) * SEQ + s]) = ch;
      }
    }
  }
}

// ================= final output projection: fp32 out, 128x128 tile =================
__global__ __launch_bounds__(256, 4) void gemm_out(const bf16_t* __restrict__ A,
                                                   const bf16_t* __restrict__ Bw,
                                                   const float* __restrict__ bias,
                                                   float* __restrict__ Cout) {
  __shared__ __align__(16) bf16_t sA[2][128 * 32]; // [64][64] swizzled view
  __shared__ __align__(16) bf16_t sB[2][128 * 32];
  const int tid = threadIdx.x;
  const int lane = tid & 63;
  const int wv = tid >> 6; // 0..3
  const int l16 = lane & 15, l4 = lane >> 4;

  int bid = blockIdx.x;
  int swz = (bid & 7) * 64 + (bid >> 3); // 512 = 8 * 64
  const int bm = swz >> 3, bn = swz & 7;
  const int m0 = bm << 7, n0 = bn << 7;
  const int wr = (wv >> 1) * 64, wc = (wv & 1) * 64;

  const int sg = (lane & 7) ^ ((lane >> 3) & 7);
  const int mS = 2 * (wv * 8 + (lane >> 3)) + (sg >> 2); // + c*64
  const int gS = (sg & 3) * 8;

  f32x4 acc[4][4] = {};

  auto stage = [&](int bb, int k0) {
#pragma unroll
    for (int c = 0; c < 2; ++c) {
      async16(A + (size_t)(m0 + c * 64 + mS) * DMODEL + k0 + gS, &sA[bb][c * 2048 + wv * 512]);
      async16(Bw + (size_t)(n0 + c * 64 + mS) * DMODEL + k0 + gS, &sB[bb][c * 2048 + wv * 512]);
    }
  };

  stage(0, 0);
  __syncthreads();
  const int NKT = DMODEL / 32; // 32
  for (int t = 0; t < NKT; ++t) {
    if (t + 1 < NKT) stage((t + 1) & 1, (t + 1) * 32);
    const bf16_t* bA = sA[t & 1];
    const bf16_t* bB = sB[t & 1];
    bf16x8 afrag[4], bfrag[4];
#pragma unroll
    for (int f = 0; f < 4; ++f) {
      afrag[f] = *reinterpret_cast<const bf16x8*>(&bA[lds_off(wr + f * 16 + l16, l4)]);
      bfrag[f] = *reinterpret_cast<const bf16x8*>(&bB[lds_off(wc + f * 16 + l16, l4)]);
    }
    __builtin_amdgcn_s_setprio(1);
#pragma unroll
    for (int i = 0; i < 4; ++i)
#pragma unroll
      for (int j = 0; j < 4; ++j)
        acc[i][j] = __builtin_amdgcn_mfma_f32_16x16x32_bf16(afrag[i], bfrag[j], acc[i][j], 0, 0, 0);
    __builtin_amdgcn_s_setprio(0);
    __syncthreads();
  }

  float bj[4];
#pragma unroll
  for (int j = 0; j < 4; ++j) bj[j] = bias[n0 + wc + j * 16 + l16];

#pragma unroll
  for (int i = 0; i < 4; ++i) {
#pragma unroll
    for (int j = 0; j < 4; ++j) {
#pragma unroll
      for (int r = 0; r < 4; ++r) {
        int m = m0 + wr + i * 16 + l4 * 4 + r;
        int n = n0 + wc + j * 16 + l16;
        Cout[(size_t)m * DMODEL + n] = acc[i][j][r] + bj[j];
      }
    }
  }
}

// ---------------- flash attention (unchanged from R4) ----------------
__device__ __forceinline__ int kvsrc_row(int r) {
  return (r & 32) | (((r >> 3) & 1) << 4) | (((r >> 2) & 1) << 3) |
         (((r >> 4) & 1) << 2) | (r & 3);
}

__global__ __launch_bounds__(512, 2) void attn_kernel(const bf16_t* __restrict__ Q,
                                                      const bf16_t* __restrict__ Kp,
                                                      const bf16_t* __restrict__ Vt,
                                                      bf16_t* __restrict__ AO) {
  __shared__ __align__(16) bf16_t sK[2][64 * 64];
  __shared__ __align__(16) bf16_t sV[2][64 * 64];
  const int tid = threadIdx.x;
  const int lane = tid & 63;
  const int wv = tid >> 6; // 0..7
  const int l16 = lane & 15, l4 = lane >> 4;
  const int sub8 = lane >> 3, c8 = lane & 7;

  const int nq = SEQ / 256; // 8
  int bid = blockIdx.x;
  int swz = (bid & 7) * 64 + (bid >> 3); // 512 blocks, bijective
  const int bh = swz / nq, qt = swz % nq;
  const int b = bh >> 4, h = bh & 15;
  const bf16_t* Qh = Q + (size_t)bh * SEQ * DK;
  const bf16_t* Kh = Kp + (size_t)bh * SEQ * DK;
  const bf16_t* Vh = Vt + (size_t)bh * DK * SEQ;
  const int q0 = qt * 256 + wv * 32;

  bf16x8 aq[2][2];
#pragma unroll
  for (int s = 0; s < 2; ++s)
#pragma unroll
    for (int hf = 0; hf < 2; ++hf)
      aq[s][hf] = *reinterpret_cast<const bf16x8*>(
          &Qh[(size_t)(q0 + s * 16 + l16) * DK + hf * 32 + l4 * 8]);

  bf16x8 ones;
#pragma unroll
  for (int i = 0; i < 8; ++i) ones[i] = (bf16_t)1.0f;

  f32x4 o[2][4] = {};
  f32x4 lacc[2] = {};

  auto stage = [&](int buf, int kv0) {
    int r = wv * 8 + sub8;
    int kvr = kvsrc_row(r);
    int cs = (c8 ^ sub8) << 3;
    async16(Kh + (size_t)(kv0 + kvr) * DK + cs, &sK[buf][wv * 512]);
    async16(Vh + (size_t)r * SEQ + kv0 + cs, &sV[buf][wv * 512]);
  };

  auto compute = [&](int buf) {
    const bf16_t* bK = sK[buf];
    const bf16_t* bV = sV[buf];
    f32x4 sc[2][4] = {};
    __builtin_amdgcn_s_setprio(1);
#pragma unroll
    for (int t = 0; t < 4; ++t) {
      bf16x8 kf0 = *reinterpret_cast<const bf16x8*>(
          &bK[(t * 16 + l16) * 64 + ((l4 ^ (l16 & 7)) << 3)]);
      bf16x8 kf1 = *reinterpret_cast<const bf16x8*>(
          &bK[(t * 16 + l16) * 64 + (((4 + l4) ^ (l16 & 7)) << 3)]);
#pragma unroll
      for (int s = 0; s < 2; ++s) {
        sc[s][t] = __builtin_amdgcn_mfma_f32_16x16x32_bf16(kf0, aq[s][0], sc[s][t], 0, 0, 0);
        sc[s][t] = __builtin_amdgcn_mfma_f32_16x16x32_bf16(kf1, aq[s][1], sc[s][t], 0, 0, 0);
      }
    }
    __builtin_amdgcn_s_setprio(0);
    bf16x8 pa[2][2];
#pragma unroll
    for (int s = 0; s < 2; ++s) {
#pragma unroll
      for (int t = 0; t < 4; ++t) {
#pragma unroll
        for (int j = 0; j < 4; ++j) {
          pa[s][t >> 1][(t & 1) * 4 + j] = (bf16_t)__builtin_amdgcn_exp2f(sc[s][t][j]);
        }
      }
    }
    __builtin_amdgcn_s_setprio(1);
#pragma unroll
    for (int nb = 0; nb < 4; ++nb) {
      bf16x8 vf0 = *reinterpret_cast<const bf16x8*>(
          &bV[(nb * 16 + l16) * 64 + ((l4 ^ (l16 & 7)) << 3)]);
      bf16x8 vf1 = *reinterpret_cast<const bf16x8*>(
          &bV[(nb * 16 + l16) * 64 + (((4 + l4) ^ (l16 & 7)) << 3)]);
#pragma unroll
      for (int s = 0; s < 2; ++s) {
        o[s][nb] = __builtin_amdgcn_mfma_f32_16x16x32_bf16(pa[s][0], vf0, o[s][nb], 0, 0, 0);
        o[s][nb] = __builtin_amdgcn_mfma_f32_16x16x32_bf16(pa[s][1], vf1, o[s][nb], 0, 0, 0);
      }
    }
#pragma unroll
    for (int s = 0; s < 2; ++s) {
      lacc[s] = __builtin_amdgcn_mfma_f32_16x16x32_bf16(pa[s][0], ones, lacc[s], 0, 0, 0);
      lacc[s] = __builtin_amdgcn_mfma_f32_16x16x32_bf16(pa[s][1], ones, lacc[s], 0, 0, 0);
    }
    __builtin_amdgcn_s_setprio(0);
  };

  stage(0, 0);
  __syncthreads();
  const int NT = SEQ / 64; // 32
  for (int it = 0; it < NT; ++it) {
    if (it + 1 < NT) stage((it + 1) & 1, (it + 1) * 64);
    compute(it & 1);
    __syncthreads();
  }

#pragma unroll
  for (int s = 0; s < 2; ++s) {
#pragma unroll
    for (int j = 0; j < 4; ++j) {
      float inv = 1.0f / lacc[s][j];
      int qrow = q0 + s * 16 + l4 * 4 + j;
#pragma unroll
      for (int nb = 0; nb < 4; ++nb)
        AO[((size_t)(b * SEQ + qrow)) * DMODEL + h * DK + nb * 16 + l16] =
            (bf16_t)(o[s][nb][j] * inv);
    }
  }
}

// ---------------- launcher ----------------
extern "C" void kernel_launch(void* const* d_in, const int* in_sizes, int n_in,
                              void* d_out, int out_size, void* d_ws, size_t ws_size,
                              hipStream_t stream) {
  const float* query = (const float*)d_in[0];
  const float* key_i = (const float*)d_in[1];
  const float* value = (const float*)d_in[2];
  const float* Wq = (const float*)d_in[3];
  const float* bq = (const float*)d_in[4];
  const float* Wk = (const float*)d_in[5];
  const float* bk = (const float*)d_in[6];
  const float* Wv = (const float*)d_in[7];
  const float* bv = (const float*)d_in[8];
  const float* Wo = (const float*)d_in[9];
  const float* bo = (const float*)d_in[10];
  float* out = (float*)d_out;

  bf16_t* wqb = (bf16_t*)d_ws;      // wqb|wkb|wvb|wob contiguous (W segments)
  bf16_t* wob = wqb + 3 * WEC;
  bf16_t* Qp = wob + WEC;           // Qp|Kp contiguous (QK output segments)
  bf16_t* Kp = Qp + NEC;
  bf16_t* Vt = Kp + NEC;
  bf16_t* AO = Vt + NEC;
  // workspace: (4*WEC + 4*NEC)*2 = 72 MiB

  cast_w<<<dim3((unsigned)(4 * WEC / 8 / 256)), dim3(256), 0, stream>>>(
      Wq, Wk, Wv, Wo, wqb);

  const float cexp = 0.18033688f; // log2(e)/8, folded into Q projection
  gemm_qkv<<<dim3(768), dim3(512), 0, stream>>>(query, key_i, value, wqb,
                                                bq, bk, bv, cexp, Qp, Vt);

  attn_kernel<<<dim3(4 * HEADS * (SEQ / 256)), 512, 0, stream>>>(Qp, Kp, Vt, AO);

  gemm_out<<<dim3(512), dim3(256), 0, stream>>>(AO, wob, bo, out);
}